// Round 11
// baseline (801.802 us; speedup 1.0000x reference)
//
#include <hip/hip_runtime.h>
#include <math.h>

#define N_NODES 50000
#define N_EDGES 800000
#define ET (N_EDGES + N_NODES)
#define N_GRAPHS 200
#define F_INN 16
#define C_DIM 64
#define N_HEADS 4
#define HIDD 256
#define SCAN_BLOCKS ((N_NODES + 255) / 256)

typedef __attribute__((ext_vector_type(8))) short short8;
typedef __attribute__((ext_vector_type(8))) ushort ushort8;
typedef __attribute__((ext_vector_type(4))) float f32x4;
typedef __attribute__((ext_vector_type(2))) float f32x2;

#define LOG2E 1.44269504088896340736f

__device__ __forceinline__ float bf2f(ushort u) {
  return __uint_as_float(((unsigned)u) << 16);
}
__device__ __forceinline__ ushort f2bf(float f) {  // round-to-nearest-even
  unsigned u = __float_as_uint(f);
  u += 0x7fff + ((u >> 16) & 1);
  return (ushort)(u >> 16);
}
__device__ __forceinline__ float ex2(float x) {
#if __has_builtin(__builtin_amdgcn_exp2f)
  return __builtin_amdgcn_exp2f(x);
#else
  return exp2f(x);
#endif
}

__device__ __forceinline__ f32x2 emax2(f32x2 a, f32x2 b) {
#if __has_builtin(__builtin_elementwise_max)
  return __builtin_elementwise_max(a, b);
#else
  f32x2 r;
  r.x = fmaxf(a.x, b.x);
  r.y = fmaxf(a.y, b.y);
  return r;
#endif
}

// ---------------- dual GEMM (fp32 vector path, layer 1 only: K=16)
// Both outputs written bf16 (Cl feeds gathers, Cr feeds scores).
template<int K, int M>
__global__ __launch_bounds__(256) void gemm_dual(
    const float* __restrict__ A, const float* __restrict__ Bl,
    const float* __restrict__ Br, ushort* __restrict__ Clb,
    ushort* __restrict__ Crb, int nrows)
{
  __shared__ __align__(16) float As[16][64];
  __shared__ __align__(16) float Bls[16][64];
  __shared__ __align__(16) float Brs[16][64];
  int tid = threadIdx.x;
  int row0 = blockIdx.x * 64;
  int col0 = blockIdx.y * 64;
  int tr = (tid >> 4) << 2;
  int tc = (tid & 15) << 2;
  float accL[4][4] = {{0.f}}, accR[4][4] = {{0.f}};
  int arow = tid >> 2, ak = (tid & 3) << 2;
  int brow = tid >> 4, bcol = (tid & 15) << 2;
  for (int k0 = 0; k0 < K; k0 += 16) {
    float4 av = make_float4(0.f, 0.f, 0.f, 0.f);
    int gr = row0 + arow;
    if (gr < nrows) av = *(const float4*)&A[(size_t)gr * K + k0 + ak];
    As[ak + 0][arow] = av.x;
    As[ak + 1][arow] = av.y;
    As[ak + 2][arow] = av.z;
    As[ak + 3][arow] = av.w;
    *(float4*)&Bls[brow][bcol] = *(const float4*)&Bl[(size_t)(k0 + brow) * M + col0 + bcol];
    *(float4*)&Brs[brow][bcol] = *(const float4*)&Br[(size_t)(k0 + brow) * M + col0 + bcol];
    __syncthreads();
    #pragma unroll
    for (int k = 0; k < 16; ++k) {
      float4 a = *(const float4*)&As[k][tr];
      float4 bl = *(const float4*)&Bls[k][tc];
      float4 br = *(const float4*)&Brs[k][tc];
      float aa[4] = {a.x, a.y, a.z, a.w};
      float lb[4] = {bl.x, bl.y, bl.z, bl.w};
      float rb[4] = {br.x, br.y, br.z, br.w};
      #pragma unroll
      for (int ii = 0; ii < 4; ++ii)
        #pragma unroll
        for (int jj = 0; jj < 4; ++jj) {
          accL[ii][jj] = fmaf(aa[ii], lb[jj], accL[ii][jj]);
          accR[ii][jj] = fmaf(aa[ii], rb[jj], accR[ii][jj]);
        }
    }
    __syncthreads();
  }
  #pragma unroll
  for (int ii = 0; ii < 4; ++ii) {
    int gr = row0 + tr + ii;
    if (gr < nrows) {
      *(ushort4*)&Clb[(size_t)gr * M + col0 + tc] =
          make_ushort4(f2bf(accL[ii][0]), f2bf(accL[ii][1]),
                       f2bf(accL[ii][2]), f2bf(accL[ii][3]));
      *(ushort4*)&Crb[(size_t)gr * M + col0 + tc] =
          make_ushort4(f2bf(accR[ii][0]), f2bf(accR[ii][1]),
                       f2bf(accR[ii][2]), f2bf(accR[ii][3]));
    }
  }
}

// ---------------- bf16x2 split helpers
__device__ __forceinline__ void split_bf16(float a, ushort& hi, ushort& lo) {
  unsigned u = __float_as_uint(a);
  hi = (ushort)(u >> 16);
  float ah = __uint_as_float(u & 0xffff0000u);
  float r = a - ah;                      // exact
  lo = (ushort)(__float_as_uint(r) >> 16);
}

// ---------------- convert a weight matrix [K][N] -> [half][K/8][N][8] bf16
template<int K, int N>
__global__ void convertB(const float* __restrict__ W, ushort* __restrict__ BTmat) {
  int idx = blockIdx.x * blockDim.x + threadIdx.x;
  if (idx >= K * N) return;
  int k = idx / N, n = idx - k * N;
  ushort hi, lo;
  split_bf16(W[idx], hi, lo);
  size_t dst = ((size_t)(k >> 3) * N + n) * 8 + (k & 7);
  BTmat[dst] = hi;
  BTmat[(size_t)(K / 8) * N * 8 + dst] = lo;
}

// ---------------- fully-fused MFMA dual GEMM (K=256), BM=32 rows/block:
//   A' = elu(bn(H)) split to bf16 hi/lo, staged in LDS (swizzled), read once.
//   LDS 34 KB -> 4 blocks/CU. Block covers 32 rows x ALL 2N combined cols.
template<int N>
__global__ __launch_bounds__(N * 2) void gemm_fused(
    const float* __restrict__ H, const float* __restrict__ gsum,
    const float* __restrict__ gsumsq, const float* __restrict__ g,
    const float* __restrict__ be, const ushort* __restrict__ BT,
    ushort* __restrict__ Clb, ushort* __restrict__ Crb)
{
  constexpr int THREADS = N * 2;
  constexpr int PLANE = 32 * N * 8;
  __shared__ float SCs[256], SHs[256];
  __shared__ ushort Ah_s[32 * 256];
  __shared__ ushort Al_s[32 * 256];
  const int tid = threadIdx.x;
  const int brow0 = blockIdx.x * 32;

  // phase 0: BN finalize in-block
  const float invn = 1.0f / (float)N_NODES;
  for (int c = tid; c < 256; c += THREADS) {
    float mu = gsum[c] * invn;
    float var = gsumsq[c] * invn - mu * mu;
    float sc = g[c] * rsqrtf(var + 1e-5f);
    SCs[c] = sc;
    SHs[c] = be[c] - mu * sc;
  }
  __syncthreads();

  // phase 1: stage 32-row A tile -> LDS, BN+ELU+bf16x2 split; XOR swizzle.
  for (int gid = tid; gid < 1024; gid += THREADS) {
    int r = gid >> 5;                 // 0..31
    int ch0 = (gid & 31) * 8;
    int grow = min(brow0 + r, N_NODES - 1);
    float4 v0 = *(const float4*)&H[(size_t)grow * 256 + ch0];
    float4 v1 = *(const float4*)&H[(size_t)grow * 256 + ch0 + 4];
    float4 sc0 = *(const float4*)&SCs[ch0];
    float4 sc1 = *(const float4*)&SCs[ch0 + 4];
    float4 sh0 = *(const float4*)&SHs[ch0];
    float4 sh1 = *(const float4*)&SHs[ch0 + 4];
    float vv[8] = {v0.x, v0.y, v0.z, v0.w, v1.x, v1.y, v1.z, v1.w};
    float scv[8] = {sc0.x, sc0.y, sc0.z, sc0.w, sc1.x, sc1.y, sc1.z, sc1.w};
    float shv[8] = {sh0.x, sh0.y, sh0.z, sh0.w, sh1.x, sh1.y, sh1.z, sh1.w};
    short8 hi8, lo8;
    #pragma unroll
    for (int j = 0; j < 8; ++j) {
      float t = fmaf(vv[j], scv[j], shv[j]);
      float e = t > 0.f ? t : __expf(t) - 1.f;
      ushort h, l;
      split_bf16(e, h, l);
      hi8[j] = (short)h;
      lo8[j] = (short)l;
    }
    int off = r * 512 + ((ch0 * 2) ^ ((r & 7) << 4));
    *(short8*)((char*)Ah_s + off) = hi8;
    *(short8*)((char*)Al_s + off) = lo8;
  }
  __syncthreads();

  // phase 2: k-loop. wave -> 64 combined cols (mat = L if combc<N else R).
  const int wave = tid >> 6, lane = tid & 63;
  const int cn = lane & 15, kgrp = lane >> 4;
  const int combc = wave * 64;
  const bool isR = combc >= N;
  const ushort* Bh = BT + (isR ? 2 * PLANE : 0);
  const ushort* Bl_ = Bh + PLANE;
  const int cb = combc & (N - 1);
  f32x4 acc[2][4];
  #pragma unroll
  for (int rt = 0; rt < 2; ++rt)
    #pragma unroll
    for (int ct = 0; ct < 4; ++ct) acc[rt][ct] = (f32x4)(0.f);

  #pragma unroll 2
  for (int k0 = 0; k0 < 256; k0 += 32) {
    short8 ah[2], al[2];
    #pragma unroll
    for (int rt = 0; rt < 2; ++rt) {
      int row = rt * 16 + cn;
      int off = row * 512 + (((k0 * 2) + kgrp * 16) ^ ((row & 7) << 4));
      ah[rt] = *(const short8*)((const char*)Ah_s + off);
      al[rt] = *(const short8*)((const char*)Al_s + off);
    }
    const size_t bbase = (size_t)((k0 >> 3) + kgrp) * (N * 8);
    #pragma unroll
    for (int ct = 0; ct < 4; ++ct) {
      const size_t bo = bbase + (size_t)(cb + ct * 16 + cn) * 8;
      short8 bh = *(const short8*)&Bh[bo];
      short8 bl = *(const short8*)&Bl_[bo];
      #pragma unroll
      for (int rt = 0; rt < 2; ++rt) {
        acc[rt][ct] = __builtin_amdgcn_mfma_f32_16x16x32_bf16(ah[rt], bh, acc[rt][ct], 0, 0, 0);
        acc[rt][ct] = __builtin_amdgcn_mfma_f32_16x16x32_bf16(ah[rt], bl, acc[rt][ct], 0, 0, 0);
        acc[rt][ct] = __builtin_amdgcn_mfma_f32_16x16x32_bf16(al[rt], bh, acc[rt][ct], 0, 0, 0);
      }
    }
  }

  // epilogue: C/D layout col=lane&15, row=(lane>>4)*4+reg  [m89 verified]
  #pragma unroll
  for (int ct = 0; ct < 4; ++ct) {
    int cc = cb + ct * 16 + cn;
    #pragma unroll
    for (int rt = 0; rt < 2; ++rt) {
      int crow0 = brow0 + rt * 16 + kgrp * 4;
      #pragma unroll
      for (int j = 0; j < 4; ++j) {
        int rr = crow0 + j;
        if (rr < N_NODES) {
          if (!isR) Clb[(size_t)rr * N + cc] = f2bf(acc[rt][ct][j]);
          else      Crb[(size_t)rr * N + cc] = f2bf(acc[rt][ct][j]);
        }
      }
    }
  }
}

// ---------------- CSR build: histogram -> multi-block scan -> scatter
__global__ void hist_kernel(const int* __restrict__ dsts, int* __restrict__ curs) {
  int i = blockIdx.x * blockDim.x + threadIdx.x;
  if (i >= ET) return;
  int d = (i < N_EDGES) ? dsts[i] : i - N_EDGES;
  atomicAdd(&curs[d], 1);
}

__global__ __launch_bounds__(256) void scan_part(
    const int* __restrict__ curs, int* __restrict__ rows, int* __restrict__ bsum)
{
  __shared__ int tmp[256];
  int t = threadIdx.x;
  int i = blockIdx.x * 256 + t;
  int v = (i < N_NODES) ? curs[i] : 0;
  tmp[t] = v;
  __syncthreads();
  #pragma unroll
  for (int off = 1; off < 256; off <<= 1) {
    int u = (t >= off) ? tmp[t - off] : 0;
    __syncthreads();
    tmp[t] += u;
    __syncthreads();
  }
  if (i < N_NODES) rows[i] = tmp[t] - v;
  if (t == 255) bsum[blockIdx.x] = tmp[255];
}

__global__ __launch_bounds__(256) void scan_bsums(
    const int* __restrict__ bsum, int* __restrict__ boff)
{
  __shared__ int tmp[256];
  int t = threadIdx.x;
  int v = (t < SCAN_BLOCKS) ? bsum[t] : 0;
  tmp[t] = v;
  __syncthreads();
  #pragma unroll
  for (int off = 1; off < 256; off <<= 1) {
    int u = (t >= off) ? tmp[t - off] : 0;
    __syncthreads();
    tmp[t] += u;
    __syncthreads();
  }
  if (t < SCAN_BLOCKS) boff[t] = tmp[t] - v;
}

__global__ __launch_bounds__(256) void scan_apply(
    int* __restrict__ rows, const int* __restrict__ boff, int* __restrict__ curs)
{
  int i = blockIdx.x * 256 + threadIdx.x;
  if (i < N_NODES) {
    int r = rows[i] + boff[blockIdx.x];
    rows[i] = r;
    curs[i] = r;
  }
  if (i == 0) rows[N_NODES] = ET;
}

__global__ void scatter_kernel(const int* __restrict__ srcs, const int* __restrict__ dsts,
                               int* __restrict__ curs, int* __restrict__ esrc) {
  int i = blockIdx.x * blockDim.x + threadIdx.x;
  if (i >= ET) return;
  int s, d;
  if (i < N_EDGES) { s = srcs[i]; d = dsts[i]; } else { s = d = i - N_EDGES; }
  int pos = atomicAdd(&curs[d], 1);
  esrc[pos] = s;
}

// ---------------- degree-sorted dst order (counting sort, descending degree).
// Balances trip counts across the waves sharing a block -> kills stragglers.
__global__ void deg_hist_kernel(const int* __restrict__ rows, int* __restrict__ dhist) {
  int i = blockIdx.x * blockDim.x + threadIdx.x;
  if (i >= N_NODES) return;
  int deg = rows[i + 1] - rows[i];
  atomicAdd(&dhist[min(deg, 63)], 1);
}
__global__ void deg_scan_kernel(const int* __restrict__ dhist, int* __restrict__ doff) {
  if (threadIdx.x == 0) {
    int acc = 0;
    for (int b = 63; b >= 0; --b) { doff[b] = acc; acc += dhist[b]; }
  }
}
__global__ void deg_scatter_kernel(const int* __restrict__ rows, int* __restrict__ doff,
                                   int* __restrict__ dord) {
  int i = blockIdx.x * blockDim.x + threadIdx.x;
  if (i >= N_NODES) return;
  int deg = rows[i + 1] - rows[i];
  int pos = atomicAdd(&doff[min(deg, 63)], 1);
  dord[pos] = i;
}

// ---------------- flash pass, D=256 (4 heads): one wave per dst (degree-
// sorted), scalar score math in exp2 domain, defer-max, unsigned saddr
// gathers, 4-edge unroll.
__global__ __launch_bounds__(256) void flash256(
    const ushort* __restrict__ xl, const ushort* __restrict__ xr,
    const float* __restrict__ att, const int* __restrict__ rows,
    const int* __restrict__ esrc, const int* __restrict__ dord,
    float* __restrict__ out)
{
  const int wave = threadIdx.x >> 6, lane = threadIdx.x & 63;
  const int d = dord[blockIdx.x * 4 + wave];   // N_NODES % 4 == 0
  const unsigned lo4 = lane * 4;
  int beg = rows[d], end = rows[d + 1];
  ushort4 ur = *(const ushort4*)&xr[(size_t)d * 256 + lo4];
  float xq0 = bf2f(ur.x), xq1 = bf2f(ur.y), xq2 = bf2f(ur.z), xq3 = bf2f(ur.w);
  float4 w = *(const float4*)&att[lo4];
  w.x *= LOG2E; w.y *= LOG2E; w.z *= LOG2E; w.w *= LOG2E;   // exp2 domain
  auto score = [&](float b0, float b1, float b2, float b3) {
    float v0 = b0 + xq0, v1 = b1 + xq1, v2 = b2 + xq2, v3 = b3 + xq3;
    v0 = v0 > 0.f ? v0 : 0.2f * v0;
    v1 = v1 > 0.f ? v1 : 0.2f * v1;
    v2 = v2 > 0.f ? v2 : 0.2f * v2;
    v3 = v3 > 0.f ? v3 : 0.2f * v3;
    return fmaf(v0, w.x, fmaf(v1, w.y, fmaf(v2, w.z, v3 * w.w)));
  };
  float m = -INFINITY, s = 0.f;
  float a0 = 0.f, a1 = 0.f, a2 = 0.f, a3 = 0.f;
  int p = beg;
  for (; p + 4 <= end; p += 4) {
    int s1 = esrc[p], s2 = esrc[p + 1], s3 = esrc[p + 2], s4 = esrc[p + 3];
    unsigned o1 = ((unsigned)s1 << 8) + lo4;
    unsigned o2 = ((unsigned)s2 << 8) + lo4;
    unsigned o3 = ((unsigned)s3 << 8) + lo4;
    unsigned o4 = ((unsigned)s4 << 8) + lo4;
    ushort4 u1 = *(const ushort4*)&xl[o1];
    ushort4 u2 = *(const ushort4*)&xl[o2];
    ushort4 u3 = *(const ushort4*)&xl[o3];
    ushort4 u4 = *(const ushort4*)&xl[o4];
    float b10 = bf2f(u1.x), b11 = bf2f(u1.y), b12 = bf2f(u1.z), b13 = bf2f(u1.w);
    float b20 = bf2f(u2.x), b21 = bf2f(u2.y), b22 = bf2f(u2.z), b23 = bf2f(u2.w);
    float b30 = bf2f(u3.x), b31 = bf2f(u3.y), b32 = bf2f(u3.z), b33 = bf2f(u3.w);
    float b40 = bf2f(u4.x), b41 = bf2f(u4.y), b42 = bf2f(u4.z), b43 = bf2f(u4.w);
    float e1 = score(b10, b11, b12, b13);
    float e2 = score(b20, b21, b22, b23);
    float e3 = score(b30, b31, b32, b33);
    float e4 = score(b40, b41, b42, b43);
    e1 += __shfl_xor(e1, 1); e2 += __shfl_xor(e2, 1);
    e3 += __shfl_xor(e3, 1); e4 += __shfl_xor(e4, 1);
    e1 += __shfl_xor(e1, 2); e2 += __shfl_xor(e2, 2);
    e3 += __shfl_xor(e3, 2); e4 += __shfl_xor(e4, 2);
    e1 += __shfl_xor(e1, 4); e2 += __shfl_xor(e2, 4);
    e3 += __shfl_xor(e3, 4); e4 += __shfl_xor(e4, 4);
    e1 += __shfl_xor(e1, 8); e2 += __shfl_xor(e2, 8);
    e3 += __shfl_xor(e3, 8); e4 += __shfl_xor(e4, 8);
    float gm = fmaxf(fmaxf(e1, e2), fmaxf(e3, e4));
    if (__all(gm <= m + 8.0f)) {        // defer-max: no rescale, p <= 2^8
      float p1 = ex2(e1 - m);
      float p2 = ex2(e2 - m);
      float p3 = ex2(e3 - m);
      float p4 = ex2(e4 - m);
      s += (p1 + p2) + (p3 + p4);
      a0 = fmaf(p1, b10, fmaf(p2, b20, fmaf(p3, b30, fmaf(p4, b40, a0))));
      a1 = fmaf(p1, b11, fmaf(p2, b21, fmaf(p3, b31, fmaf(p4, b41, a1))));
      a2 = fmaf(p1, b12, fmaf(p2, b22, fmaf(p3, b32, fmaf(p4, b42, a2))));
      a3 = fmaf(p1, b13, fmaf(p2, b23, fmaf(p3, b33, fmaf(p4, b43, a3))));
    } else {
      float mn = fmaxf(m, gm);
      float f = ex2(m - mn);
      float p1 = ex2(e1 - mn);
      float p2 = ex2(e2 - mn);
      float p3 = ex2(e3 - mn);
      float p4 = ex2(e4 - mn);
      s = s * f + ((p1 + p2) + (p3 + p4));
      a0 = fmaf(a0, f, fmaf(p1, b10, fmaf(p2, b20, fmaf(p3, b30, p4 * b40))));
      a1 = fmaf(a1, f, fmaf(p1, b11, fmaf(p2, b21, fmaf(p3, b31, p4 * b41))));
      a2 = fmaf(a2, f, fmaf(p1, b12, fmaf(p2, b22, fmaf(p3, b32, p4 * b42))));
      a3 = fmaf(a3, f, fmaf(p1, b13, fmaf(p2, b23, fmaf(p3, b33, p4 * b43))));
      m = mn;
    }
  }
  for (; p < end; ++p) {
    int s1 = esrc[p];
    unsigned o1 = ((unsigned)s1 << 8) + lo4;
    ushort4 u1 = *(const ushort4*)&xl[o1];
    float b10 = bf2f(u1.x), b11 = bf2f(u1.y), b12 = bf2f(u1.z), b13 = bf2f(u1.w);
    float e1 = score(b10, b11, b12, b13);
    e1 += __shfl_xor(e1, 1);
    e1 += __shfl_xor(e1, 2);
    e1 += __shfl_xor(e1, 4);
    e1 += __shfl_xor(e1, 8);
    float mn = fmaxf(m, e1);
    float f = ex2(m - mn);
    float p1 = ex2(e1 - mn);
    s = fmaf(s, f, p1);
    a0 = fmaf(a0, f, p1 * b10);
    a1 = fmaf(a1, f, p1 * b11);
    a2 = fmaf(a2, f, p1 * b12);
    a3 = fmaf(a3, f, p1 * b13);
    m = mn;
  }
  float inv = 1.f / (s + 1e-16f);
  *(float4*)&out[(size_t)d * 256 + lo4] =
      make_float4(a0 * inv, a1 * inv, a2 * inv, a3 * inv);
}

// ---------------- flash pass, D=64 (1 head): 8 lanes per dst, 8 dsts/wave
// (degree-sorted -> similar trip counts), exp2 domain, defer-max.
__global__ __launch_bounds__(256) void flash64(
    const ushort* __restrict__ xl, const ushort* __restrict__ xr,
    const float* __restrict__ att, const int* __restrict__ rows,
    const int* __restrict__ esrc, const int* __restrict__ dord,
    float* __restrict__ out)
{
  const int wave = threadIdx.x >> 6, lane = threadIdx.x & 63;
  const int di = lane >> 3, sl = lane & 7;
  const int idx = blockIdx.x * 32 + wave * 8 + di;
  const bool valid = idx < N_NODES;
  const int d = dord[valid ? idx : 0];
  const unsigned ch = sl * 8;
  ushort8 uxr = *(const ushort8*)&xr[(size_t)d * 64 + ch];
  float4 wa = *(const float4*)&att[ch];
  float4 wb = *(const float4*)&att[ch + 4];
  f32x2 xr0 = {bf2f(uxr[0]), bf2f(uxr[1])}, xr1 = {bf2f(uxr[2]), bf2f(uxr[3])};
  f32x2 xr2 = {bf2f(uxr[4]), bf2f(uxr[5])}, xr3 = {bf2f(uxr[6]), bf2f(uxr[7])};
  f32x2 w0 = {wa.x * LOG2E, wa.y * LOG2E}, w1 = {wa.z * LOG2E, wa.w * LOG2E};
  f32x2 w2 = {wb.x * LOG2E, wb.y * LOG2E}, w3 = {wb.z * LOG2E, wb.w * LOG2E};
  int beg = rows[d], end = rows[d + 1];
  float m = -INFINITY, s = 0.f;
  f32x2 a0 = {0.f, 0.f}, a1 = {0.f, 0.f}, a2 = {0.f, 0.f}, a3 = {0.f, 0.f};

  auto loadb = [&](int src, f32x2 b[4]) {
    unsigned off = ((unsigned)src << 6) + ch;
    ushort8 u = *(const ushort8*)&xl[off];
    b[0] = f32x2{bf2f(u[0]), bf2f(u[1])};
    b[1] = f32x2{bf2f(u[2]), bf2f(u[3])};
    b[2] = f32x2{bf2f(u[4]), bf2f(u[5])};
    b[3] = f32x2{bf2f(u[6]), bf2f(u[7])};
  };
  auto scoreP = [&](const f32x2 b[4]) -> float {
    f32x2 v0 = b[0] + xr0, v1 = b[1] + xr1, v2 = b[2] + xr2, v3 = b[3] + xr3;
    v0 = emax2(v0, v0 * 0.2f);
    v1 = emax2(v1, v1 * 0.2f);
    v2 = emax2(v2, v2 * 0.2f);
    v3 = emax2(v3, v3 * 0.2f);
    f32x2 dd = (v0 * w0 + v1 * w1) + (v2 * w2 + v3 * w3);
    return dd.x + dd.y;
  };
  auto one_edge = [&](int src) {
    f32x2 b[4];
    loadb(src, b);
    float e = scoreP(b);
    e += __shfl_xor(e, 1);
    e += __shfl_xor(e, 2);
    e += __shfl_xor(e, 4);
    float mn = fmaxf(m, e);
    float f = ex2(m - mn);
    float pe = ex2(e - mn);
    s = s * f + pe;
    a0 = a0 * f + b[0] * pe;
    a1 = a1 * f + b[1] * pe;
    a2 = a2 * f + b[2] * pe;
    a3 = a3 * f + b[3] * pe;
    m = mn;
  };

  int p = beg;
  int hd = min(end, (beg + 3) & ~3);
  for (; p < hd; ++p) one_edge(esrc[p]);
  for (; p + 4 <= end; p += 4) {
    int4 sv = *(const int4*)&esrc[p];
    f32x2 b1[4], b2[4], b3[4], b4[4];
    loadb(sv.x, b1);
    loadb(sv.y, b2);
    loadb(sv.z, b3);
    loadb(sv.w, b4);
    float e1 = scoreP(b1);
    float e2 = scoreP(b2);
    float e3 = scoreP(b3);
    float e4 = scoreP(b4);
    e1 += __shfl_xor(e1, 1); e2 += __shfl_xor(e2, 1);
    e3 += __shfl_xor(e3, 1); e4 += __shfl_xor(e4, 1);
    e1 += __shfl_xor(e1, 2); e2 += __shfl_xor(e2, 2);
    e3 += __shfl_xor(e3, 2); e4 += __shfl_xor(e4, 2);
    e1 += __shfl_xor(e1, 4); e2 += __shfl_xor(e2, 4);
    e3 += __shfl_xor(e3, 4); e4 += __shfl_xor(e4, 4);
    float gm = fmaxf(fmaxf(e1, e2), fmaxf(e3, e4));
    if (__all(gm <= m + 8.0f)) {
      float p1 = ex2(e1 - m);
      float p2 = ex2(e2 - m);
      float p3 = ex2(e3 - m);
      float p4 = ex2(e4 - m);
      s += (p1 + p2) + (p3 + p4);
      a0 = a0 + ((b1[0] * p1 + b2[0] * p2) + (b3[0] * p3 + b4[0] * p4));
      a1 = a1 + ((b1[1] * p1 + b2[1] * p2) + (b3[1] * p3 + b4[1] * p4));
      a2 = a2 + ((b1[2] * p1 + b2[2] * p2) + (b3[2] * p3 + b4[2] * p4));
      a3 = a3 + ((b1[3] * p1 + b2[3] * p2) + (b3[3] * p3 + b4[3] * p4));
    } else {
      float mn = fmaxf(m, gm);
      float f = ex2(m - mn);
      float p1 = ex2(e1 - mn);
      float p2 = ex2(e2 - mn);
      float p3 = ex2(e3 - mn);
      float p4 = ex2(e4 - mn);
      s = s * f + ((p1 + p2) + (p3 + p4));
      a0 = a0 * f + ((b1[0] * p1 + b2[0] * p2) + (b3[0] * p3 + b4[0] * p4));
      a1 = a1 * f + ((b1[1] * p1 + b2[1] * p2) + (b3[1] * p3 + b4[1] * p4));
      a2 = a2 * f + ((b1[2] * p1 + b2[2] * p2) + (b3[2] * p3 + b4[2] * p4));
      a3 = a3 * f + ((b1[3] * p1 + b2[3] * p2) + (b3[3] * p3 + b4[3] * p4));
      m = mn;
    }
  }
  for (; p < end; ++p) one_edge(esrc[p]);

  if (valid) {
    float inv = 1.f / (s + 1e-16f);
    *(float4*)&out[(size_t)d * 64 + ch] =
        make_float4(a0.x * inv, a0.y * inv, a1.x * inv, a1.y * inv);
    *(float4*)&out[(size_t)d * 64 + ch + 4] =
        make_float4(a2.x * inv, a2.y * inv, a3.x * inv, a3.y * inv);
  }
}

// ---------------- BN statistics (per-channel sum / sumsq)
template<int D_, int RPB>
__global__ __launch_bounds__(256) void bn_stats(const float* __restrict__ h,
    float* __restrict__ gsum, float* __restrict__ gsumsq, int nrows)
{
  constexpr int RG = 256 / D_;
  int c = threadIdx.x % D_;
  int rg = threadIdx.x / D_;
  int r0 = blockIdx.x * RPB;
  float s = 0.f, sq = 0.f;
  int rend = min(r0 + RPB, nrows);
  for (int r = r0 + rg; r < rend; r += RG) {
    float v = h[(size_t)r * D_ + c];
    s += v;
    sq = fmaf(v, v, sq);
  }
  atomicAdd(&gsum[c], s);
  atomicAdd(&gsumsq[c], sq);
}

// ---------------- fused pooling (BN finalize+apply inline) + classifier MLP.
__global__ __launch_bounds__(256) void pool_mlp(
    const float* __restrict__ h3, const int* __restrict__ batch,
    const float* __restrict__ gsum, const float* __restrict__ gsumsq,
    const float* __restrict__ g3, const float* __restrict__ be3,
    const float* __restrict__ Wc1, const float* __restrict__ bc1,
    const float* __restrict__ Wc2, const float* __restrict__ bc2,
    float* __restrict__ outp)
{
  int g = blockIdx.x;
  int t = threadIdx.x;
  int lane = t & 63, w = t >> 6;
  int lo, hi;
  {
    int a = 0, b = N_NODES;
    while (a < b) { int mid = (a + b) >> 1; if (batch[mid] < g) a = mid + 1; else b = mid; }
    lo = a;
    b = N_NODES;
    while (a < b) { int mid = (a + b) >> 1; if (batch[mid] < g + 1) a = mid + 1; else b = mid; }
    hi = a;
  }
  const float invn = 1.0f / (float)N_NODES;
  float mu = gsum[lane] * invn;
  float var = gsumsq[lane] * invn - mu * mu;
  float scl = g3[lane] * rsqrtf(var + 1e-5f);
  float shf = be3[lane] - mu * scl;
  float s = 0.f, mx = -INFINITY;
  for (int r = lo + w; r < hi; r += 4) {
    float v = fmaf(h3[(size_t)r * 64 + lane], scl, shf);
    s += v;
    mx = fmaxf(mx, v);
  }
  __shared__ float ssum[4][64];
  __shared__ float smax[4][64];
  __shared__ float pooled[128];
  ssum[w][lane] = s;
  smax[w][lane] = mx;
  __syncthreads();
  if (w == 0) {
    float tot = ssum[0][lane] + ssum[1][lane] + ssum[2][lane] + ssum[3][lane];
    float m4 = fmaxf(fmaxf(smax[0][lane], smax[1][lane]),
                     fmaxf(smax[2][lane], smax[3][lane]));
    float cnt = (float)(hi - lo);
    pooled[lane] = tot / fmaxf(cnt, 1.f);
    pooled[64 + lane] = m4;
  }
  __syncthreads();
  if (w == 0) {
    float a = bc1[lane];
    #pragma unroll 8
    for (int k = 0; k < 128; ++k) a = fmaf(pooled[k], Wc1[k * 64 + lane], a);
    a = fmaxf(a, 0.f);
    float v = a * Wc2[lane];
    v += __shfl_xor(v, 1);
    v += __shfl_xor(v, 2);
    v += __shfl_xor(v, 4);
    v += __shfl_xor(v, 8);
    v += __shfl_xor(v, 16);
    v += __shfl_xor(v, 32);
    if (lane == 0) outp[g] = v + bc2[0];
  }
}

extern "C" void kernel_launch(void* const* d_in, const int* in_sizes, int n_in,
                              void* d_out, int out_size, void* d_ws, size_t ws_size,
                              hipStream_t stream)
{
  const float* x    = (const float*)d_in[0];
  const int*   ei   = (const int*)d_in[1];
  const int*   batch= (const int*)d_in[2];
  const float* Wl1  = (const float*)d_in[3];
  const float* Wr1  = (const float*)d_in[4];
  const float* att1 = (const float*)d_in[5];
  // b1/b2/b3 cancel in the following BatchNorm -> unused
  const float* g1   = (const float*)d_in[7];
  const float* be1  = (const float*)d_in[8];
  const float* Wl2  = (const float*)d_in[9];
  const float* Wr2  = (const float*)d_in[10];
  const float* att2 = (const float*)d_in[11];
  const float* g2   = (const float*)d_in[13];
  const float* be2  = (const float*)d_in[14];
  const float* Wl3  = (const float*)d_in[15];
  const float* Wr3  = (const float*)d_in[16];
  const float* att3 = (const float*)d_in[17];
  const float* g3   = (const float*)d_in[19];
  const float* be3  = (const float*)d_in[20];
  const float* Wc1  = (const float*)d_in[21];
  const float* bc1  = (const float*)d_in[22];
  const float* Wc2  = (const float*)d_in[23];
  const float* bc2  = (const float*)d_in[24];

  const int* srcs = ei;
  const int* dsts = ei + N_EDGES;

  float* ws = (float*)d_ws;
  size_t o = 0;
  ushort* XLB = (ushort*)(ws + o); o += (size_t)N_NODES * HIDD / 2;  // bf16 xl
  ushort* XRB = (ushort*)(ws + o); o += (size_t)N_NODES * HIDD / 2;  // bf16 xr
  float* Hb = ws + o;            o += (size_t)N_NODES * HIDD;
  ushort* BT2 = (ushort*)(ws + o); o += (size_t)4 * 32 * 256 * 8 / 2;   // 2 mats x 2 halves
  ushort* BT3 = (ushort*)(ws + o); o += (size_t)4 * 32 * 64 * 8 / 2;
  int* ESRC = (int*)(ws + o);    o += ET;
  int* ROWS = (int*)(ws + o);    o += N_NODES + 1;
  int* CURS = (int*)(ws + o);    o += N_NODES;
  int* DHIST = (int*)(ws + o);   o += 64;
  int* DOFF = (int*)(ws + o);    o += 64;
  int* DORD = (int*)(ws + o);    o += N_NODES;
  int* BSUM = (int*)(ws + o);    o += SCAN_BLOCKS;
  int* BOFF = (int*)(ws + o);    o += SCAN_BLOCKS;
  float* GS  = ws + o;           o += 256;
  float* GSQ = ws + o;           o += 256;

  const int ROW_BLOCKS = (N_NODES + 63) / 64;
  const int ROW_BLOCKS32 = (N_NODES + 31) / 32;
  const int DST_BLOCKS = (N_NODES + 3) / 4;
  constexpr int PLANE2 = 32 * 256 * 8;
  constexpr int PLANE3 = 32 * 64 * 8;

  // ================= weight transpose/split (independent; run once up front)
  convertB<256, 256><<<(65536 + 255) / 256, 256, 0, stream>>>(Wl2, BT2);
  convertB<256, 256><<<(65536 + 255) / 256, 256, 0, stream>>>(Wr2, BT2 + 2 * PLANE2);
  convertB<256, 64><<<(16384 + 255) / 256, 256, 0, stream>>>(Wl3, BT3);
  convertB<256, 64><<<(16384 + 255) / 256, 256, 0, stream>>>(Wr3, BT3 + 2 * PLANE3);

  // ================= CSR build + degree-sorted dst order ==================
  hipMemsetAsync(CURS, 0, (N_NODES + 64) * 4, stream);   // CURS + DHIST
  hist_kernel<<<(ET + 255) / 256, 256, 0, stream>>>(dsts, CURS);
  scan_part<<<SCAN_BLOCKS, 256, 0, stream>>>(CURS, ROWS, BSUM);
  scan_bsums<<<1, 256, 0, stream>>>(BSUM, BOFF);
  scan_apply<<<SCAN_BLOCKS, 256, 0, stream>>>(ROWS, BOFF, CURS);
  scatter_kernel<<<(ET + 255) / 256, 256, 0, stream>>>(srcs, dsts, CURS, ESRC);
  deg_hist_kernel<<<SCAN_BLOCKS, 256, 0, stream>>>(ROWS, DHIST);
  deg_scan_kernel<<<1, 64, 0, stream>>>(DHIST, DOFF);
  deg_scatter_kernel<<<SCAN_BLOCKS, 256, 0, stream>>>(ROWS, DOFF, DORD);

  // ================= layer 1 (16 -> 4x64, concat): fp32 vector GEMM ======
  gemm_dual<16, 256><<<dim3(ROW_BLOCKS, 4), 256, 0, stream>>>(
      x, Wl1, Wr1, XLB, XRB, N_NODES);
  flash256<<<DST_BLOCKS, 256, 0, stream>>>(XLB, XRB, att1, ROWS, ESRC, DORD, Hb);
  hipMemsetAsync(GS, 0, 512 * 4, stream);
  bn_stats<256, 64><<<ROW_BLOCKS, 256, 0, stream>>>(Hb, GS, GSQ, N_NODES);

  // ================= layer 2 (256 -> 4x64): fully-fused BN+ELU+MFMA GEMM ==
  gemm_fused<256><<<ROW_BLOCKS32, 512, 0, stream>>>(
      Hb, GS, GSQ, g1, be1, BT2, XLB, XRB);
  flash256<<<DST_BLOCKS, 256, 0, stream>>>(XLB, XRB, att2, ROWS, ESRC, DORD, Hb);
  hipMemsetAsync(GS, 0, 512 * 4, stream);
  bn_stats<256, 64><<<ROW_BLOCKS, 256, 0, stream>>>(Hb, GS, GSQ, N_NODES);

  // ================= layer 3 (256 -> 64, 1 head): fused MFMA GEMM ========
  gemm_fused<64><<<ROW_BLOCKS32, 128, 0, stream>>>(
      Hb, GS, GSQ, g2, be2, BT3, XLB, XRB);
  flash64<<<(N_NODES + 31) / 32, 256, 0, stream>>>(XLB, XRB, att3, ROWS, ESRC, DORD, Hb);
  hipMemsetAsync(GS, 0, 512 * 4, stream);
  bn_stats<64, 256><<<(N_NODES + 255) / 256, 256, 0, stream>>>(Hb, GS, GSQ, N_NODES);

  // ================= fused pooling (BN inline) + classifier ==============
  pool_mlp<<<N_GRAPHS, 256, 0, stream>>>(Hb, batch, GS, GSQ, g3, be3,
                                         Wc1, bc1, Wc2, bc2, (float*)d_out);
}

// Round 12
// 542.591 us; speedup vs baseline: 1.4777x; 1.4777x over previous
//
#include <hip/hip_runtime.h>
#include <math.h>

#define N_NODES 50000
#define N_EDGES 800000
#define ET (N_EDGES + N_NODES)
#define N_GRAPHS 200
#define F_INN 16
#define C_DIM 64
#define N_HEADS 4
#define HIDD 256
#define SCAN_BLOCKS ((N_NODES + 255) / 256)

typedef __attribute__((ext_vector_type(8))) short short8;
typedef __attribute__((ext_vector_type(8))) ushort ushort8;
typedef __attribute__((ext_vector_type(4))) float f32x4;
typedef __attribute__((ext_vector_type(2))) float f32x2;

#define LOG2E 1.44269504088896340736f

__device__ __forceinline__ float bf2f(ushort u) {
  return __uint_as_float(((unsigned)u) << 16);
}
__device__ __forceinline__ ushort f2bf(float f) {  // round-to-nearest-even
  unsigned u = __float_as_uint(f);
  u += 0x7fff + ((u >> 16) & 1);
  return (ushort)(u >> 16);
}
__device__ __forceinline__ float ex2(float x) {
#if __has_builtin(__builtin_amdgcn_exp2f)
  return __builtin_amdgcn_exp2f(x);
#else
  return exp2f(x);
#endif
}

__device__ __forceinline__ f32x2 emax2(f32x2 a, f32x2 b) {
#if __has_builtin(__builtin_elementwise_max)
  return __builtin_elementwise_max(a, b);
#else
  f32x2 r;
  r.x = fmaxf(a.x, b.x);
  r.y = fmaxf(a.y, b.y);
  return r;
#endif
}

// ---------------- dual GEMM (fp32 vector path, layer 1 only: K=16)
// Both outputs written bf16 (Cl feeds gathers, Cr feeds scores).
template<int K, int M>
__global__ __launch_bounds__(256) void gemm_dual(
    const float* __restrict__ A, const float* __restrict__ Bl,
    const float* __restrict__ Br, ushort* __restrict__ Clb,
    ushort* __restrict__ Crb, int nrows)
{
  __shared__ __align__(16) float As[16][64];
  __shared__ __align__(16) float Bls[16][64];
  __shared__ __align__(16) float Brs[16][64];
  int tid = threadIdx.x;
  int row0 = blockIdx.x * 64;
  int col0 = blockIdx.y * 64;
  int tr = (tid >> 4) << 2;
  int tc = (tid & 15) << 2;
  float accL[4][4] = {{0.f}}, accR[4][4] = {{0.f}};
  int arow = tid >> 2, ak = (tid & 3) << 2;
  int brow = tid >> 4, bcol = (tid & 15) << 2;
  for (int k0 = 0; k0 < K; k0 += 16) {
    float4 av = make_float4(0.f, 0.f, 0.f, 0.f);
    int gr = row0 + arow;
    if (gr < nrows) av = *(const float4*)&A[(size_t)gr * K + k0 + ak];
    As[ak + 0][arow] = av.x;
    As[ak + 1][arow] = av.y;
    As[ak + 2][arow] = av.z;
    As[ak + 3][arow] = av.w;
    *(float4*)&Bls[brow][bcol] = *(const float4*)&Bl[(size_t)(k0 + brow) * M + col0 + bcol];
    *(float4*)&Brs[brow][bcol] = *(const float4*)&Br[(size_t)(k0 + brow) * M + col0 + bcol];
    __syncthreads();
    #pragma unroll
    for (int k = 0; k < 16; ++k) {
      float4 a = *(const float4*)&As[k][tr];
      float4 bl = *(const float4*)&Bls[k][tc];
      float4 br = *(const float4*)&Brs[k][tc];
      float aa[4] = {a.x, a.y, a.z, a.w};
      float lb[4] = {bl.x, bl.y, bl.z, bl.w};
      float rb[4] = {br.x, br.y, br.z, br.w};
      #pragma unroll
      for (int ii = 0; ii < 4; ++ii)
        #pragma unroll
        for (int jj = 0; jj < 4; ++jj) {
          accL[ii][jj] = fmaf(aa[ii], lb[jj], accL[ii][jj]);
          accR[ii][jj] = fmaf(aa[ii], rb[jj], accR[ii][jj]);
        }
    }
    __syncthreads();
  }
  #pragma unroll
  for (int ii = 0; ii < 4; ++ii) {
    int gr = row0 + tr + ii;
    if (gr < nrows) {
      *(ushort4*)&Clb[(size_t)gr * M + col0 + tc] =
          make_ushort4(f2bf(accL[ii][0]), f2bf(accL[ii][1]),
                       f2bf(accL[ii][2]), f2bf(accL[ii][3]));
      *(ushort4*)&Crb[(size_t)gr * M + col0 + tc] =
          make_ushort4(f2bf(accR[ii][0]), f2bf(accR[ii][1]),
                       f2bf(accR[ii][2]), f2bf(accR[ii][3]));
    }
  }
}

// ---------------- bf16x2 split helpers
__device__ __forceinline__ void split_bf16(float a, ushort& hi, ushort& lo) {
  unsigned u = __float_as_uint(a);
  hi = (ushort)(u >> 16);
  float ah = __uint_as_float(u & 0xffff0000u);
  float r = a - ah;                      // exact
  lo = (ushort)(__float_as_uint(r) >> 16);
}

// ---------------- convert a weight matrix [K][N] -> [half][K/8][N][8] bf16
template<int K, int N>
__global__ void convertB(const float* __restrict__ W, ushort* __restrict__ BTmat) {
  int idx = blockIdx.x * blockDim.x + threadIdx.x;
  if (idx >= K * N) return;
  int k = idx / N, n = idx - k * N;
  ushort hi, lo;
  split_bf16(W[idx], hi, lo);
  size_t dst = ((size_t)(k >> 3) * N + n) * 8 + (k & 7);
  BTmat[dst] = hi;
  BTmat[(size_t)(K / 8) * N * 8 + dst] = lo;
}

// ---------------- fully-fused MFMA dual GEMM (K=256), BM=32 rows/block:
//   A' = elu(bn(H)) split to bf16 hi/lo, staged in LDS (swizzled), read once.
//   LDS 34 KB -> 4 blocks/CU. Block covers 32 rows x ALL 2N combined cols.
template<int N>
__global__ __launch_bounds__(N * 2) void gemm_fused(
    const float* __restrict__ H, const float* __restrict__ gsum,
    const float* __restrict__ gsumsq, const float* __restrict__ g,
    const float* __restrict__ be, const ushort* __restrict__ BT,
    ushort* __restrict__ Clb, ushort* __restrict__ Crb)
{
  constexpr int THREADS = N * 2;
  constexpr int PLANE = 32 * N * 8;
  __shared__ float SCs[256], SHs[256];
  __shared__ ushort Ah_s[32 * 256];
  __shared__ ushort Al_s[32 * 256];
  const int tid = threadIdx.x;
  const int brow0 = blockIdx.x * 32;

  // phase 0: BN finalize in-block
  const float invn = 1.0f / (float)N_NODES;
  for (int c = tid; c < 256; c += THREADS) {
    float mu = gsum[c] * invn;
    float var = gsumsq[c] * invn - mu * mu;
    float sc = g[c] * rsqrtf(var + 1e-5f);
    SCs[c] = sc;
    SHs[c] = be[c] - mu * sc;
  }
  __syncthreads();

  // phase 1: stage 32-row A tile -> LDS, BN+ELU+bf16x2 split; XOR swizzle.
  for (int gid = tid; gid < 1024; gid += THREADS) {
    int r = gid >> 5;                 // 0..31
    int ch0 = (gid & 31) * 8;
    int grow = min(brow0 + r, N_NODES - 1);
    float4 v0 = *(const float4*)&H[(size_t)grow * 256 + ch0];
    float4 v1 = *(const float4*)&H[(size_t)grow * 256 + ch0 + 4];
    float4 sc0 = *(const float4*)&SCs[ch0];
    float4 sc1 = *(const float4*)&SCs[ch0 + 4];
    float4 sh0 = *(const float4*)&SHs[ch0];
    float4 sh1 = *(const float4*)&SHs[ch0 + 4];
    float vv[8] = {v0.x, v0.y, v0.z, v0.w, v1.x, v1.y, v1.z, v1.w};
    float scv[8] = {sc0.x, sc0.y, sc0.z, sc0.w, sc1.x, sc1.y, sc1.z, sc1.w};
    float shv[8] = {sh0.x, sh0.y, sh0.z, sh0.w, sh1.x, sh1.y, sh1.z, sh1.w};
    short8 hi8, lo8;
    #pragma unroll
    for (int j = 0; j < 8; ++j) {
      float t = fmaf(vv[j], scv[j], shv[j]);
      float e = t > 0.f ? t : __expf(t) - 1.f;
      ushort h, l;
      split_bf16(e, h, l);
      hi8[j] = (short)h;
      lo8[j] = (short)l;
    }
    int off = r * 512 + ((ch0 * 2) ^ ((r & 7) << 4));
    *(short8*)((char*)Ah_s + off) = hi8;
    *(short8*)((char*)Al_s + off) = lo8;
  }
  __syncthreads();

  // phase 2: k-loop. wave -> 64 combined cols (mat = L if combc<N else R).
  const int wave = tid >> 6, lane = tid & 63;
  const int cn = lane & 15, kgrp = lane >> 4;
  const int combc = wave * 64;
  const bool isR = combc >= N;
  const ushort* Bh = BT + (isR ? 2 * PLANE : 0);
  const ushort* Bl_ = Bh + PLANE;
  const int cb = combc & (N - 1);
  f32x4 acc[2][4];
  #pragma unroll
  for (int rt = 0; rt < 2; ++rt)
    #pragma unroll
    for (int ct = 0; ct < 4; ++ct) acc[rt][ct] = (f32x4)(0.f);

  #pragma unroll 2
  for (int k0 = 0; k0 < 256; k0 += 32) {
    short8 ah[2], al[2];
    #pragma unroll
    for (int rt = 0; rt < 2; ++rt) {
      int row = rt * 16 + cn;
      int off = row * 512 + (((k0 * 2) + kgrp * 16) ^ ((row & 7) << 4));
      ah[rt] = *(const short8*)((const char*)Ah_s + off);
      al[rt] = *(const short8*)((const char*)Al_s + off);
    }
    const size_t bbase = (size_t)((k0 >> 3) + kgrp) * (N * 8);
    #pragma unroll
    for (int ct = 0; ct < 4; ++ct) {
      const size_t bo = bbase + (size_t)(cb + ct * 16 + cn) * 8;
      short8 bh = *(const short8*)&Bh[bo];
      short8 bl = *(const short8*)&Bl_[bo];
      #pragma unroll
      for (int rt = 0; rt < 2; ++rt) {
        acc[rt][ct] = __builtin_amdgcn_mfma_f32_16x16x32_bf16(ah[rt], bh, acc[rt][ct], 0, 0, 0);
        acc[rt][ct] = __builtin_amdgcn_mfma_f32_16x16x32_bf16(ah[rt], bl, acc[rt][ct], 0, 0, 0);
        acc[rt][ct] = __builtin_amdgcn_mfma_f32_16x16x32_bf16(al[rt], bh, acc[rt][ct], 0, 0, 0);
      }
    }
  }

  // epilogue: C/D layout col=lane&15, row=(lane>>4)*4+reg  [m89 verified]
  #pragma unroll
  for (int ct = 0; ct < 4; ++ct) {
    int cc = cb + ct * 16 + cn;
    #pragma unroll
    for (int rt = 0; rt < 2; ++rt) {
      int crow0 = brow0 + rt * 16 + kgrp * 4;
      #pragma unroll
      for (int j = 0; j < 4; ++j) {
        int rr = crow0 + j;
        if (rr < N_NODES) {
          if (!isR) Clb[(size_t)rr * N + cc] = f2bf(acc[rt][ct][j]);
          else      Crb[(size_t)rr * N + cc] = f2bf(acc[rt][ct][j]);
        }
      }
    }
  }
}

// ---------------- CSR build: histogram -> multi-block scan -> scatter
__global__ void hist_kernel(const int* __restrict__ dsts, int* __restrict__ curs) {
  int i = blockIdx.x * blockDim.x + threadIdx.x;
  if (i >= ET) return;
  int d = (i < N_EDGES) ? dsts[i] : i - N_EDGES;
  atomicAdd(&curs[d], 1);
}

__global__ __launch_bounds__(256) void scan_part(
    const int* __restrict__ curs, int* __restrict__ rows, int* __restrict__ bsum)
{
  __shared__ int tmp[256];
  int t = threadIdx.x;
  int i = blockIdx.x * 256 + t;
  int v = (i < N_NODES) ? curs[i] : 0;
  tmp[t] = v;
  __syncthreads();
  #pragma unroll
  for (int off = 1; off < 256; off <<= 1) {
    int u = (t >= off) ? tmp[t - off] : 0;
    __syncthreads();
    tmp[t] += u;
    __syncthreads();
  }
  if (i < N_NODES) rows[i] = tmp[t] - v;
  if (t == 255) bsum[blockIdx.x] = tmp[255];
}

__global__ __launch_bounds__(256) void scan_bsums(
    const int* __restrict__ bsum, int* __restrict__ boff)
{
  __shared__ int tmp[256];
  int t = threadIdx.x;
  int v = (t < SCAN_BLOCKS) ? bsum[t] : 0;
  tmp[t] = v;
  __syncthreads();
  #pragma unroll
  for (int off = 1; off < 256; off <<= 1) {
    int u = (t >= off) ? tmp[t - off] : 0;
    __syncthreads();
    tmp[t] += u;
    __syncthreads();
  }
  if (t < SCAN_BLOCKS) boff[t] = tmp[t] - v;
}

__global__ __launch_bounds__(256) void scan_apply(
    int* __restrict__ rows, const int* __restrict__ boff, int* __restrict__ curs)
{
  int i = blockIdx.x * 256 + threadIdx.x;
  if (i < N_NODES) {
    int r = rows[i] + boff[blockIdx.x];
    rows[i] = r;
    curs[i] = r;
  }
  if (i == 0) rows[N_NODES] = ET;
}

__global__ void scatter_kernel(const int* __restrict__ srcs, const int* __restrict__ dsts,
                               int* __restrict__ curs, int* __restrict__ esrc) {
  int i = blockIdx.x * blockDim.x + threadIdx.x;
  if (i >= ET) return;
  int s, d;
  if (i < N_EDGES) { s = srcs[i]; d = dsts[i]; } else { s = d = i - N_EDGES; }
  int pos = atomicAdd(&curs[d], 1);
  esrc[pos] = s;
}

// ---------------- flash pass, D=256 (4 heads): one wave per dst, scalar
// score math in exp2 domain, defer-max, unsigned saddr gathers, 4-edge unroll.
__global__ __launch_bounds__(256) void flash256(
    const ushort* __restrict__ xl, const ushort* __restrict__ xr,
    const float* __restrict__ att, const int* __restrict__ rows,
    const int* __restrict__ esrc, float* __restrict__ out)
{
  const int wave = threadIdx.x >> 6, lane = threadIdx.x & 63;
  const int d = blockIdx.x * 4 + wave;   // N_NODES % 4 == 0
  const unsigned lo4 = lane * 4;
  int beg = rows[d], end = rows[d + 1];
  ushort4 ur = *(const ushort4*)&xr[(size_t)d * 256 + lo4];
  float xq0 = bf2f(ur.x), xq1 = bf2f(ur.y), xq2 = bf2f(ur.z), xq3 = bf2f(ur.w);
  float4 w = *(const float4*)&att[lo4];
  w.x *= LOG2E; w.y *= LOG2E; w.z *= LOG2E; w.w *= LOG2E;   // exp2 domain
  auto score = [&](float b0, float b1, float b2, float b3) {
    float v0 = b0 + xq0, v1 = b1 + xq1, v2 = b2 + xq2, v3 = b3 + xq3;
    v0 = v0 > 0.f ? v0 : 0.2f * v0;
    v1 = v1 > 0.f ? v1 : 0.2f * v1;
    v2 = v2 > 0.f ? v2 : 0.2f * v2;
    v3 = v3 > 0.f ? v3 : 0.2f * v3;
    return fmaf(v0, w.x, fmaf(v1, w.y, fmaf(v2, w.z, v3 * w.w)));
  };
  float m = -INFINITY, s = 0.f;
  float a0 = 0.f, a1 = 0.f, a2 = 0.f, a3 = 0.f;
  int p = beg;
  for (; p + 4 <= end; p += 4) {
    int s1 = esrc[p], s2 = esrc[p + 1], s3 = esrc[p + 2], s4 = esrc[p + 3];
    unsigned o1 = ((unsigned)s1 << 8) + lo4;
    unsigned o2 = ((unsigned)s2 << 8) + lo4;
    unsigned o3 = ((unsigned)s3 << 8) + lo4;
    unsigned o4 = ((unsigned)s4 << 8) + lo4;
    ushort4 u1 = *(const ushort4*)&xl[o1];
    ushort4 u2 = *(const ushort4*)&xl[o2];
    ushort4 u3 = *(const ushort4*)&xl[o3];
    ushort4 u4 = *(const ushort4*)&xl[o4];
    float b10 = bf2f(u1.x), b11 = bf2f(u1.y), b12 = bf2f(u1.z), b13 = bf2f(u1.w);
    float b20 = bf2f(u2.x), b21 = bf2f(u2.y), b22 = bf2f(u2.z), b23 = bf2f(u2.w);
    float b30 = bf2f(u3.x), b31 = bf2f(u3.y), b32 = bf2f(u3.z), b33 = bf2f(u3.w);
    float b40 = bf2f(u4.x), b41 = bf2f(u4.y), b42 = bf2f(u4.z), b43 = bf2f(u4.w);
    float e1 = score(b10, b11, b12, b13);
    float e2 = score(b20, b21, b22, b23);
    float e3 = score(b30, b31, b32, b33);
    float e4 = score(b40, b41, b42, b43);
    e1 += __shfl_xor(e1, 1); e2 += __shfl_xor(e2, 1);
    e3 += __shfl_xor(e3, 1); e4 += __shfl_xor(e4, 1);
    e1 += __shfl_xor(e1, 2); e2 += __shfl_xor(e2, 2);
    e3 += __shfl_xor(e3, 2); e4 += __shfl_xor(e4, 2);
    e1 += __shfl_xor(e1, 4); e2 += __shfl_xor(e2, 4);
    e3 += __shfl_xor(e3, 4); e4 += __shfl_xor(e4, 4);
    e1 += __shfl_xor(e1, 8); e2 += __shfl_xor(e2, 8);
    e3 += __shfl_xor(e3, 8); e4 += __shfl_xor(e4, 8);
    float gm = fmaxf(fmaxf(e1, e2), fmaxf(e3, e4));
    if (__all(gm <= m + 8.0f)) {        // defer-max: no rescale, p <= 2^8
      float p1 = ex2(e1 - m);
      float p2 = ex2(e2 - m);
      float p3 = ex2(e3 - m);
      float p4 = ex2(e4 - m);
      s += (p1 + p2) + (p3 + p4);
      a0 = fmaf(p1, b10, fmaf(p2, b20, fmaf(p3, b30, fmaf(p4, b40, a0))));
      a1 = fmaf(p1, b11, fmaf(p2, b21, fmaf(p3, b31, fmaf(p4, b41, a1))));
      a2 = fmaf(p1, b12, fmaf(p2, b22, fmaf(p3, b32, fmaf(p4, b42, a2))));
      a3 = fmaf(p1, b13, fmaf(p2, b23, fmaf(p3, b33, fmaf(p4, b43, a3))));
    } else {
      float mn = fmaxf(m, gm);
      float f = ex2(m - mn);
      float p1 = ex2(e1 - mn);
      float p2 = ex2(e2 - mn);
      float p3 = ex2(e3 - mn);
      float p4 = ex2(e4 - mn);
      s = s * f + ((p1 + p2) + (p3 + p4));
      a0 = fmaf(a0, f, fmaf(p1, b10, fmaf(p2, b20, fmaf(p3, b30, p4 * b40))));
      a1 = fmaf(a1, f, fmaf(p1, b11, fmaf(p2, b21, fmaf(p3, b31, p4 * b41))));
      a2 = fmaf(a2, f, fmaf(p1, b12, fmaf(p2, b22, fmaf(p3, b32, p4 * b42))));
      a3 = fmaf(a3, f, fmaf(p1, b13, fmaf(p2, b23, fmaf(p3, b33, p4 * b43))));
      m = mn;
    }
  }
  for (; p < end; ++p) {
    int s1 = esrc[p];
    unsigned o1 = ((unsigned)s1 << 8) + lo4;
    ushort4 u1 = *(const ushort4*)&xl[o1];
    float b10 = bf2f(u1.x), b11 = bf2f(u1.y), b12 = bf2f(u1.z), b13 = bf2f(u1.w);
    float e1 = score(b10, b11, b12, b13);
    e1 += __shfl_xor(e1, 1);
    e1 += __shfl_xor(e1, 2);
    e1 += __shfl_xor(e1, 4);
    e1 += __shfl_xor(e1, 8);
    float mn = fmaxf(m, e1);
    float f = ex2(m - mn);
    float p1 = ex2(e1 - mn);
    s = fmaf(s, f, p1);
    a0 = fmaf(a0, f, p1 * b10);
    a1 = fmaf(a1, f, p1 * b11);
    a2 = fmaf(a2, f, p1 * b12);
    a3 = fmaf(a3, f, p1 * b13);
    m = mn;
  }
  float inv = 1.f / (s + 1e-16f);
  *(float4*)&out[(size_t)d * 256 + lo4] =
      make_float4(a0 * inv, a1 * inv, a2 * inv, a3 * inv);
}

// ---------------- flash pass, D=64 (1 head): 8 lanes per dst, 8 dsts/wave,
// exp2 domain, defer-max, unsigned saddr gathers.
__global__ __launch_bounds__(256) void flash64(
    const ushort* __restrict__ xl, const ushort* __restrict__ xr,
    const float* __restrict__ att, const int* __restrict__ rows,
    const int* __restrict__ esrc, float* __restrict__ out)
{
  const int wave = threadIdx.x >> 6, lane = threadIdx.x & 63;
  const int di = lane >> 3, sl = lane & 7;
  const int idx = blockIdx.x * 32 + wave * 8 + di;
  const bool valid = idx < N_NODES;
  const int d = valid ? idx : N_NODES - 1;
  const unsigned ch = sl * 8;
  ushort8 uxr = *(const ushort8*)&xr[(size_t)d * 64 + ch];
  float4 wa = *(const float4*)&att[ch];
  float4 wb = *(const float4*)&att[ch + 4];
  f32x2 xr0 = {bf2f(uxr[0]), bf2f(uxr[1])}, xr1 = {bf2f(uxr[2]), bf2f(uxr[3])};
  f32x2 xr2 = {bf2f(uxr[4]), bf2f(uxr[5])}, xr3 = {bf2f(uxr[6]), bf2f(uxr[7])};
  f32x2 w0 = {wa.x * LOG2E, wa.y * LOG2E}, w1 = {wa.z * LOG2E, wa.w * LOG2E};
  f32x2 w2 = {wb.x * LOG2E, wb.y * LOG2E}, w3 = {wb.z * LOG2E, wb.w * LOG2E};
  int beg = rows[d], end = rows[d + 1];
  float m = -INFINITY, s = 0.f;
  f32x2 a0 = {0.f, 0.f}, a1 = {0.f, 0.f}, a2 = {0.f, 0.f}, a3 = {0.f, 0.f};

  auto loadb = [&](int src, f32x2 b[4]) {
    unsigned off = ((unsigned)src << 6) + ch;
    ushort8 u = *(const ushort8*)&xl[off];
    b[0] = f32x2{bf2f(u[0]), bf2f(u[1])};
    b[1] = f32x2{bf2f(u[2]), bf2f(u[3])};
    b[2] = f32x2{bf2f(u[4]), bf2f(u[5])};
    b[3] = f32x2{bf2f(u[6]), bf2f(u[7])};
  };
  auto scoreP = [&](const f32x2 b[4]) -> float {
    f32x2 v0 = b[0] + xr0, v1 = b[1] + xr1, v2 = b[2] + xr2, v3 = b[3] + xr3;
    v0 = emax2(v0, v0 * 0.2f);
    v1 = emax2(v1, v1 * 0.2f);
    v2 = emax2(v2, v2 * 0.2f);
    v3 = emax2(v3, v3 * 0.2f);
    f32x2 dd = (v0 * w0 + v1 * w1) + (v2 * w2 + v3 * w3);
    return dd.x + dd.y;
  };
  auto one_edge = [&](int src) {
    f32x2 b[4];
    loadb(src, b);
    float e = scoreP(b);
    e += __shfl_xor(e, 1);
    e += __shfl_xor(e, 2);
    e += __shfl_xor(e, 4);
    float mn = fmaxf(m, e);
    float f = ex2(m - mn);
    float pe = ex2(e - mn);
    s = s * f + pe;
    a0 = a0 * f + b[0] * pe;
    a1 = a1 * f + b[1] * pe;
    a2 = a2 * f + b[2] * pe;
    a3 = a3 * f + b[3] * pe;
    m = mn;
  };

  int p = beg;
  int hd = min(end, (beg + 3) & ~3);
  for (; p < hd; ++p) one_edge(esrc[p]);
  for (; p + 4 <= end; p += 4) {
    int4 sv = *(const int4*)&esrc[p];
    f32x2 b1[4], b2[4], b3[4], b4[4];
    loadb(sv.x, b1);
    loadb(sv.y, b2);
    loadb(sv.z, b3);
    loadb(sv.w, b4);
    float e1 = scoreP(b1);
    float e2 = scoreP(b2);
    float e3 = scoreP(b3);
    float e4 = scoreP(b4);
    e1 += __shfl_xor(e1, 1); e2 += __shfl_xor(e2, 1);
    e3 += __shfl_xor(e3, 1); e4 += __shfl_xor(e4, 1);
    e1 += __shfl_xor(e1, 2); e2 += __shfl_xor(e2, 2);
    e3 += __shfl_xor(e3, 2); e4 += __shfl_xor(e4, 2);
    e1 += __shfl_xor(e1, 4); e2 += __shfl_xor(e2, 4);
    e3 += __shfl_xor(e3, 4); e4 += __shfl_xor(e4, 4);
    float gm = fmaxf(fmaxf(e1, e2), fmaxf(e3, e4));
    if (__all(gm <= m + 8.0f)) {
      float p1 = ex2(e1 - m);
      float p2 = ex2(e2 - m);
      float p3 = ex2(e3 - m);
      float p4 = ex2(e4 - m);
      s += (p1 + p2) + (p3 + p4);
      a0 = a0 + ((b1[0] * p1 + b2[0] * p2) + (b3[0] * p3 + b4[0] * p4));
      a1 = a1 + ((b1[1] * p1 + b2[1] * p2) + (b3[1] * p3 + b4[1] * p4));
      a2 = a2 + ((b1[2] * p1 + b2[2] * p2) + (b3[2] * p3 + b4[2] * p4));
      a3 = a3 + ((b1[3] * p1 + b2[3] * p2) + (b3[3] * p3 + b4[3] * p4));
    } else {
      float mn = fmaxf(m, gm);
      float f = ex2(m - mn);
      float p1 = ex2(e1 - mn);
      float p2 = ex2(e2 - mn);
      float p3 = ex2(e3 - mn);
      float p4 = ex2(e4 - mn);
      s = s * f + ((p1 + p2) + (p3 + p4));
      a0 = a0 * f + ((b1[0] * p1 + b2[0] * p2) + (b3[0] * p3 + b4[0] * p4));
      a1 = a1 * f + ((b1[1] * p1 + b2[1] * p2) + (b3[1] * p3 + b4[1] * p4));
      a2 = a2 * f + ((b1[2] * p1 + b2[2] * p2) + (b3[2] * p3 + b4[2] * p4));
      a3 = a3 * f + ((b1[3] * p1 + b2[3] * p2) + (b3[3] * p3 + b4[3] * p4));
      m = mn;
    }
  }
  for (; p < end; ++p) one_edge(esrc[p]);

  if (valid) {
    float inv = 1.f / (s + 1e-16f);
    *(float4*)&out[(size_t)d * 64 + ch] =
        make_float4(a0.x * inv, a0.y * inv, a1.x * inv, a1.y * inv);
    *(float4*)&out[(size_t)d * 64 + ch + 4] =
        make_float4(a2.x * inv, a2.y * inv, a3.x * inv, a3.y * inv);
  }
}

// ---------------- BN statistics (per-channel sum / sumsq)
template<int D_, int RPB>
__global__ __launch_bounds__(256) void bn_stats(const float* __restrict__ h,
    float* __restrict__ gsum, float* __restrict__ gsumsq, int nrows)
{
  constexpr int RG = 256 / D_;
  int c = threadIdx.x % D_;
  int rg = threadIdx.x / D_;
  int r0 = blockIdx.x * RPB;
  float s = 0.f, sq = 0.f;
  int rend = min(r0 + RPB, nrows);
  for (int r = r0 + rg; r < rend; r += RG) {
    float v = h[(size_t)r * D_ + c];
    s += v;
    sq = fmaf(v, v, sq);
  }
  atomicAdd(&gsum[c], s);
  atomicAdd(&gsumsq[c], sq);
}

// ---------------- fused pooling (BN finalize+apply inline) + classifier MLP.
__global__ __launch_bounds__(256) void pool_mlp(
    const float* __restrict__ h3, const int* __restrict__ batch,
    const float* __restrict__ gsum, const float* __restrict__ gsumsq,
    const float* __restrict__ g3, const float* __restrict__ be3,
    const float* __restrict__ Wc1, const float* __restrict__ bc1,
    const float* __restrict__ Wc2, const float* __restrict__ bc2,
    float* __restrict__ outp)
{
  int g = blockIdx.x;
  int t = threadIdx.x;
  int lane = t & 63, w = t >> 6;
  int lo, hi;
  {
    int a = 0, b = N_NODES;
    while (a < b) { int mid = (a + b) >> 1; if (batch[mid] < g) a = mid + 1; else b = mid; }
    lo = a;
    b = N_NODES;
    while (a < b) { int mid = (a + b) >> 1; if (batch[mid] < g + 1) a = mid + 1; else b = mid; }
    hi = a;
  }
  const float invn = 1.0f / (float)N_NODES;
  float mu = gsum[lane] * invn;
  float var = gsumsq[lane] * invn - mu * mu;
  float scl = g3[lane] * rsqrtf(var + 1e-5f);
  float shf = be3[lane] - mu * scl;
  float s = 0.f, mx = -INFINITY;
  for (int r = lo + w; r < hi; r += 4) {
    float v = fmaf(h3[(size_t)r * 64 + lane], scl, shf);
    s += v;
    mx = fmaxf(mx, v);
  }
  __shared__ float ssum[4][64];
  __shared__ float smax[4][64];
  __shared__ float pooled[128];
  ssum[w][lane] = s;
  smax[w][lane] = mx;
  __syncthreads();
  if (w == 0) {
    float tot = ssum[0][lane] + ssum[1][lane] + ssum[2][lane] + ssum[3][lane];
    float m4 = fmaxf(fmaxf(smax[0][lane], smax[1][lane]),
                     fmaxf(smax[2][lane], smax[3][lane]));
    float cnt = (float)(hi - lo);
    pooled[lane] = tot / fmaxf(cnt, 1.f);
    pooled[64 + lane] = m4;
  }
  __syncthreads();
  if (w == 0) {
    float a = bc1[lane];
    #pragma unroll 8
    for (int k = 0; k < 128; ++k) a = fmaf(pooled[k], Wc1[k * 64 + lane], a);
    a = fmaxf(a, 0.f);
    float v = a * Wc2[lane];
    v += __shfl_xor(v, 1);
    v += __shfl_xor(v, 2);
    v += __shfl_xor(v, 4);
    v += __shfl_xor(v, 8);
    v += __shfl_xor(v, 16);
    v += __shfl_xor(v, 32);
    if (lane == 0) outp[g] = v + bc2[0];
  }
}

extern "C" void kernel_launch(void* const* d_in, const int* in_sizes, int n_in,
                              void* d_out, int out_size, void* d_ws, size_t ws_size,
                              hipStream_t stream)
{
  const float* x    = (const float*)d_in[0];
  const int*   ei   = (const int*)d_in[1];
  const int*   batch= (const int*)d_in[2];
  const float* Wl1  = (const float*)d_in[3];
  const float* Wr1  = (const float*)d_in[4];
  const float* att1 = (const float*)d_in[5];
  // b1/b2/b3 cancel in the following BatchNorm -> unused
  const float* g1   = (const float*)d_in[7];
  const float* be1  = (const float*)d_in[8];
  const float* Wl2  = (const float*)d_in[9];
  const float* Wr2  = (const float*)d_in[10];
  const float* att2 = (const float*)d_in[11];
  const float* g2   = (const float*)d_in[13];
  const float* be2  = (const float*)d_in[14];
  const float* Wl3  = (const float*)d_in[15];
  const float* Wr3  = (const float*)d_in[16];
  const float* att3 = (const float*)d_in[17];
  const float* g3   = (const float*)d_in[19];
  const float* be3  = (const float*)d_in[20];
  const float* Wc1  = (const float*)d_in[21];
  const float* bc1  = (const float*)d_in[22];
  const float* Wc2  = (const float*)d_in[23];
  const float* bc2  = (const float*)d_in[24];

  const int* srcs = ei;
  const int* dsts = ei + N_EDGES;

  float* ws = (float*)d_ws;
  size_t o = 0;
  ushort* XLB = (ushort*)(ws + o); o += (size_t)N_NODES * HIDD / 2;  // bf16 xl
  ushort* XRB = (ushort*)(ws + o); o += (size_t)N_NODES * HIDD / 2;  // bf16 xr
  float* Hb = ws + o;            o += (size_t)N_NODES * HIDD;
  ushort* BT2 = (ushort*)(ws + o); o += (size_t)4 * 32 * 256 * 8 / 2;   // 2 mats x 2 halves
  ushort* BT3 = (ushort*)(ws + o); o += (size_t)4 * 32 * 64 * 8 / 2;
  int* ESRC = (int*)(ws + o);    o += ET;
  int* ROWS = (int*)(ws + o);    o += N_NODES + 1;
  int* CURS = (int*)(ws + o);    o += N_NODES;
  int* BSUM = (int*)(ws + o);    o += SCAN_BLOCKS;
  int* BOFF = (int*)(ws + o);    o += SCAN_BLOCKS;
  float* GS  = ws + o;           o += 256;
  float* GSQ = ws + o;           o += 256;

  const int ROW_BLOCKS = (N_NODES + 63) / 64;
  const int ROW_BLOCKS32 = (N_NODES + 31) / 32;
  const int DST_BLOCKS = (N_NODES + 3) / 4;
  constexpr int PLANE2 = 32 * 256 * 8;
  constexpr int PLANE3 = 32 * 64 * 8;

  // ================= weight transpose/split (independent; run once up front)
  convertB<256, 256><<<(65536 + 255) / 256, 256, 0, stream>>>(Wl2, BT2);
  convertB<256, 256><<<(65536 + 255) / 256, 256, 0, stream>>>(Wr2, BT2 + 2 * PLANE2);
  convertB<256, 64><<<(16384 + 255) / 256, 256, 0, stream>>>(Wl3, BT3);
  convertB<256, 64><<<(16384 + 255) / 256, 256, 0, stream>>>(Wr3, BT3 + 2 * PLANE3);

  // ================= CSR build (reused by all 3 layers) =================
  hipMemsetAsync(CURS, 0, N_NODES * 4, stream);
  hist_kernel<<<(ET + 255) / 256, 256, 0, stream>>>(dsts, CURS);
  scan_part<<<SCAN_BLOCKS, 256, 0, stream>>>(CURS, ROWS, BSUM);
  scan_bsums<<<1, 256, 0, stream>>>(BSUM, BOFF);
  scan_apply<<<SCAN_BLOCKS, 256, 0, stream>>>(ROWS, BOFF, CURS);
  scatter_kernel<<<(ET + 255) / 256, 256, 0, stream>>>(srcs, dsts, CURS, ESRC);

  // ================= layer 1 (16 -> 4x64, concat): fp32 vector GEMM ======
  gemm_dual<16, 256><<<dim3(ROW_BLOCKS, 4), 256, 0, stream>>>(
      x, Wl1, Wr1, XLB, XRB, N_NODES);
  flash256<<<DST_BLOCKS, 256, 0, stream>>>(XLB, XRB, att1, ROWS, ESRC, Hb);
  hipMemsetAsync(GS, 0, 512 * 4, stream);
  bn_stats<256, 64><<<ROW_BLOCKS, 256, 0, stream>>>(Hb, GS, GSQ, N_NODES);

  // ================= layer 2 (256 -> 4x64): fully-fused BN+ELU+MFMA GEMM ==
  gemm_fused<256><<<ROW_BLOCKS32, 512, 0, stream>>>(
      Hb, GS, GSQ, g1, be1, BT2, XLB, XRB);
  flash256<<<DST_BLOCKS, 256, 0, stream>>>(XLB, XRB, att2, ROWS, ESRC, Hb);
  hipMemsetAsync(GS, 0, 512 * 4, stream);
  bn_stats<256, 64><<<ROW_BLOCKS, 256, 0, stream>>>(Hb, GS, GSQ, N_NODES);

  // ================= layer 3 (256 -> 64, 1 head): fused MFMA GEMM ========
  gemm_fused<64><<<ROW_BLOCKS32, 128, 0, stream>>>(
      Hb, GS, GSQ, g2, be2, BT3, XLB, XRB);
  flash64<<<(N_NODES + 31) / 32, 256, 0, stream>>>(XLB, XRB, att3, ROWS, ESRC, Hb);
  hipMemsetAsync(GS, 0, 512 * 4, stream);
  bn_stats<64, 256><<<(N_NODES + 255) / 256, 256, 0, stream>>>(Hb, GS, GSQ, N_NODES);

  // ================= fused pooling (BN inline) + classifier ==============
  pool_mlp<<<N_GRAPHS, 256, 0, stream>>>(Hb, batch, GS, GSQ, g3, be3,
                                         Wc1, bc1, Wc2, bc2, (float*)d_out);
}

// Round 14
// 530.477 us; speedup vs baseline: 1.5115x; 1.0228x over previous
//
#include <hip/hip_runtime.h>
#include <math.h>

#define N_NODES 50000
#define N_EDGES 800000
#define ET (N_EDGES + N_NODES)
#define N_GRAPHS 200
#define F_INN 16
#define C_DIM 64
#define N_HEADS 4
#define HIDD 256
#define SCAN_BLOCKS ((N_NODES + 255) / 256)

typedef __attribute__((ext_vector_type(8))) short short8;
typedef __attribute__((ext_vector_type(8))) ushort ushort8;
typedef __attribute__((ext_vector_type(4))) float f32x4;
typedef __attribute__((ext_vector_type(2))) float f32x2;
typedef __attribute__((ext_vector_type(2))) _Float16 h16x2;

#define LOG2E 1.44269504088896340736f

__device__ __forceinline__ float ex2(float x) {
#if __has_builtin(__builtin_amdgcn_exp2f)
  return __builtin_amdgcn_exp2f(x);
#else
  return exp2f(x);
#endif
}

__device__ __forceinline__ h16x2 bc16(unsigned u) {
  union { unsigned u; h16x2 h; } c; c.u = u; return c.h;
}
__device__ __forceinline__ ushort f2h(float f) {
  union { _Float16 h; ushort u; } c; c.h = (_Float16)f; return c.u;
}

#if __has_builtin(__builtin_amdgcn_cvt_pkrtz)
using hw2 = decltype(__builtin_amdgcn_cvt_pkrtz(0.f, 0.f));
__device__ __forceinline__ h16x2 pkrtz(float a, float b) {
  union { hw2 w; h16x2 h; } c;
  c.w = __builtin_amdgcn_cvt_pkrtz(a, b);
  return c.h;
}
#else
__device__ __forceinline__ h16x2 pkrtz(float a, float b) {
  h16x2 r; r[0] = (_Float16)a; r[1] = (_Float16)b; return r;
}
#endif

__device__ __forceinline__ float fdot2f(h16x2 a, h16x2 b, float c) {
#if __has_builtin(__builtin_amdgcn_fdot2) && __has_builtin(__builtin_amdgcn_cvt_pkrtz)
  union { h16x2 h; hw2 w; } ca, cb;
  ca.h = a; cb.h = b;
  return __builtin_amdgcn_fdot2(ca.w, cb.w, c, false);
#else
  return (float)a[0] * (float)b[0] + (float)a[1] * (float)b[1] + c;
#endif
}
__device__ __forceinline__ h16x2 hmax2(h16x2 a, h16x2 b) {
#if __has_builtin(__builtin_elementwise_max)
  return __builtin_elementwise_max(a, b);
#else
  h16x2 r; r[0] = a[0] > b[0] ? a[0] : b[0]; r[1] = a[1] > b[1] ? a[1] : b[1]; return r;
#endif
}
__device__ __forceinline__ unsigned permu(unsigned s0, unsigned s1, unsigned sel) {
#if __has_builtin(__builtin_amdgcn_perm)
  return __builtin_amdgcn_perm(s0, s1, sel);
#else
  unsigned long long cat = (((unsigned long long)s0) << 32) | s1;
  unsigned r = 0;
  for (int i = 0; i < 4; ++i) {
    unsigned b = (sel >> (8 * i)) & 0xff;
    r |= ((unsigned)((cat >> (8 * (b & 7))) & 0xff)) << (8 * i);
  }
  return r;
#endif
}
// pair_lo(A,B) -> (A.low16, B.low16) ; pair_hi -> (A.high16, B.high16)
#define PAIR_LO(A, B) permu((B), (A), 0x05040100u)
#define PAIR_HI(A, B) permu((B), (A), 0x07060302u)

// ---------------- dual GEMM (fp32 vector path, layer 1 only: K=16)
// Both outputs written fp16 (Cl feeds gathers, Cr feeds scores).
template<int K, int M>
__global__ __launch_bounds__(256) void gemm_dual(
    const float* __restrict__ A, const float* __restrict__ Bl,
    const float* __restrict__ Br, ushort* __restrict__ Clb,
    ushort* __restrict__ Crb, int nrows)
{
  __shared__ __align__(16) float As[16][64];
  __shared__ __align__(16) float Bls[16][64];
  __shared__ __align__(16) float Brs[16][64];
  int tid = threadIdx.x;
  int row0 = blockIdx.x * 64;
  int col0 = blockIdx.y * 64;
  int tr = (tid >> 4) << 2;
  int tc = (tid & 15) << 2;
  float accL[4][4] = {{0.f}}, accR[4][4] = {{0.f}};
  int arow = tid >> 2, ak = (tid & 3) << 2;
  int brow = tid >> 4, bcol = (tid & 15) << 2;
  for (int k0 = 0; k0 < K; k0 += 16) {
    float4 av = make_float4(0.f, 0.f, 0.f, 0.f);
    int gr = row0 + arow;
    if (gr < nrows) av = *(const float4*)&A[(size_t)gr * K + k0 + ak];
    As[ak + 0][arow] = av.x;
    As[ak + 1][arow] = av.y;
    As[ak + 2][arow] = av.z;
    As[ak + 3][arow] = av.w;
    *(float4*)&Bls[brow][bcol] = *(const float4*)&Bl[(size_t)(k0 + brow) * M + col0 + bcol];
    *(float4*)&Brs[brow][bcol] = *(const float4*)&Br[(size_t)(k0 + brow) * M + col0 + bcol];
    __syncthreads();
    #pragma unroll
    for (int k = 0; k < 16; ++k) {
      float4 a = *(const float4*)&As[k][tr];
      float4 bl = *(const float4*)&Bls[k][tc];
      float4 br = *(const float4*)&Brs[k][tc];
      float aa[4] = {a.x, a.y, a.z, a.w};
      float lb[4] = {bl.x, bl.y, bl.z, bl.w};
      float rb[4] = {br.x, br.y, br.z, br.w};
      #pragma unroll
      for (int ii = 0; ii < 4; ++ii)
        #pragma unroll
        for (int jj = 0; jj < 4; ++jj) {
          accL[ii][jj] = fmaf(aa[ii], lb[jj], accL[ii][jj]);
          accR[ii][jj] = fmaf(aa[ii], rb[jj], accR[ii][jj]);
        }
    }
    __syncthreads();
  }
  #pragma unroll
  for (int ii = 0; ii < 4; ++ii) {
    int gr = row0 + tr + ii;
    if (gr < nrows) {
      *(ushort4*)&Clb[(size_t)gr * M + col0 + tc] =
          make_ushort4(f2h(accL[ii][0]), f2h(accL[ii][1]),
                       f2h(accL[ii][2]), f2h(accL[ii][3]));
      *(ushort4*)&Crb[(size_t)gr * M + col0 + tc] =
          make_ushort4(f2h(accR[ii][0]), f2h(accR[ii][1]),
                       f2h(accR[ii][2]), f2h(accR[ii][3]));
    }
  }
}

// ---------------- bf16x2 split helpers (GEMM inputs stay bf16x2-split)
__device__ __forceinline__ void split_bf16(float a, ushort& hi, ushort& lo) {
  unsigned u = __float_as_uint(a);
  hi = (ushort)(u >> 16);
  float ah = __uint_as_float(u & 0xffff0000u);
  float r = a - ah;                      // exact
  lo = (ushort)(__float_as_uint(r) >> 16);
}

// ---------------- convert a weight matrix [K][N] -> [half][K/8][N][8] bf16
template<int K, int N>
__global__ void convertB(const float* __restrict__ W, ushort* __restrict__ BTmat) {
  int idx = blockIdx.x * blockDim.x + threadIdx.x;
  if (idx >= K * N) return;
  int k = idx / N, n = idx - k * N;
  ushort hi, lo;
  split_bf16(W[idx], hi, lo);
  size_t dst = ((size_t)(k >> 3) * N + n) * 8 + (k & 7);
  BTmat[dst] = hi;
  BTmat[(size_t)(K / 8) * N * 8 + dst] = lo;
}

// ---------------- fully-fused MFMA dual GEMM (K=256), BM=32 rows/block:
//   A' = elu(bn(H)) split to bf16 hi/lo, staged in LDS (swizzled), read once.
//   Outputs written fp16.
template<int N>
__global__ __launch_bounds__(N * 2) void gemm_fused(
    const float* __restrict__ H, const float* __restrict__ gsum,
    const float* __restrict__ gsumsq, const float* __restrict__ g,
    const float* __restrict__ be, const ushort* __restrict__ BT,
    ushort* __restrict__ Clb, ushort* __restrict__ Crb)
{
  constexpr int THREADS = N * 2;
  constexpr int PLANE = 32 * N * 8;
  __shared__ float SCs[256], SHs[256];
  __shared__ ushort Ah_s[32 * 256];
  __shared__ ushort Al_s[32 * 256];
  const int tid = threadIdx.x;
  const int brow0 = blockIdx.x * 32;

  // phase 0: BN finalize in-block
  const float invn = 1.0f / (float)N_NODES;
  for (int c = tid; c < 256; c += THREADS) {
    float mu = gsum[c] * invn;
    float var = gsumsq[c] * invn - mu * mu;
    float sc = g[c] * rsqrtf(var + 1e-5f);
    SCs[c] = sc;
    SHs[c] = be[c] - mu * sc;
  }
  __syncthreads();

  // phase 1: stage 32-row A tile -> LDS, BN+ELU+bf16x2 split; XOR swizzle.
  for (int gid = tid; gid < 1024; gid += THREADS) {
    int r = gid >> 5;
    int ch0 = (gid & 31) * 8;
    int grow = min(brow0 + r, N_NODES - 1);
    float4 v0 = *(const float4*)&H[(size_t)grow * 256 + ch0];
    float4 v1 = *(const float4*)&H[(size_t)grow * 256 + ch0 + 4];
    float4 sc0 = *(const float4*)&SCs[ch0];
    float4 sc1 = *(const float4*)&SCs[ch0 + 4];
    float4 sh0 = *(const float4*)&SHs[ch0];
    float4 sh1 = *(const float4*)&SHs[ch0 + 4];
    float vv[8] = {v0.x, v0.y, v0.z, v0.w, v1.x, v1.y, v1.z, v1.w};
    float scv[8] = {sc0.x, sc0.y, sc0.z, sc0.w, sc1.x, sc1.y, sc1.z, sc1.w};
    float shv[8] = {sh0.x, sh0.y, sh0.z, sh0.w, sh1.x, sh1.y, sh1.z, sh1.w};
    short8 hi8, lo8;
    #pragma unroll
    for (int j = 0; j < 8; ++j) {
      float t = fmaf(vv[j], scv[j], shv[j]);
      float e = t > 0.f ? t : __expf(t) - 1.f;
      ushort h, l;
      split_bf16(e, h, l);
      hi8[j] = (short)h;
      lo8[j] = (short)l;
    }
    int off = r * 512 + ((ch0 * 2) ^ ((r & 7) << 4));
    *(short8*)((char*)Ah_s + off) = hi8;
    *(short8*)((char*)Al_s + off) = lo8;
  }
  __syncthreads();

  // phase 2: k-loop. wave -> 64 combined cols (mat = L if combc<N else R).
  const int wave = tid >> 6, lane = tid & 63;
  const int cn = lane & 15, kgrp = lane >> 4;
  const int combc = wave * 64;
  const bool isR = combc >= N;
  const ushort* Bh = BT + (isR ? 2 * PLANE : 0);
  const ushort* Bl_ = Bh + PLANE;
  const int cb = combc & (N - 1);
  f32x4 acc[2][4];
  #pragma unroll
  for (int rt = 0; rt < 2; ++rt)
    #pragma unroll
    for (int ct = 0; ct < 4; ++ct) acc[rt][ct] = (f32x4)(0.f);

  #pragma unroll 2
  for (int k0 = 0; k0 < 256; k0 += 32) {
    short8 ah[2], al[2];
    #pragma unroll
    for (int rt = 0; rt < 2; ++rt) {
      int row = rt * 16 + cn;
      int off = row * 512 + (((k0 * 2) + kgrp * 16) ^ ((row & 7) << 4));
      ah[rt] = *(const short8*)((const char*)Ah_s + off);
      al[rt] = *(const short8*)((const char*)Al_s + off);
    }
    const size_t bbase = (size_t)((k0 >> 3) + kgrp) * (N * 8);
    #pragma unroll
    for (int ct = 0; ct < 4; ++ct) {
      const size_t bo = bbase + (size_t)(cb + ct * 16 + cn) * 8;
      short8 bh = *(const short8*)&Bh[bo];
      short8 bl = *(const short8*)&Bl_[bo];
      #pragma unroll
      for (int rt = 0; rt < 2; ++rt) {
        acc[rt][ct] = __builtin_amdgcn_mfma_f32_16x16x32_bf16(ah[rt], bh, acc[rt][ct], 0, 0, 0);
        acc[rt][ct] = __builtin_amdgcn_mfma_f32_16x16x32_bf16(ah[rt], bl, acc[rt][ct], 0, 0, 0);
        acc[rt][ct] = __builtin_amdgcn_mfma_f32_16x16x32_bf16(al[rt], bh, acc[rt][ct], 0, 0, 0);
      }
    }
  }

  // epilogue: C/D layout col=lane&15, row=(lane>>4)*4+reg  [m89 verified]
  #pragma unroll
  for (int ct = 0; ct < 4; ++ct) {
    int cc = cb + ct * 16 + cn;
    #pragma unroll
    for (int rt = 0; rt < 2; ++rt) {
      int crow0 = brow0 + rt * 16 + kgrp * 4;
      #pragma unroll
      for (int j = 0; j < 4; ++j) {
        int rr = crow0 + j;
        if (rr < N_NODES) {
          if (!isR) Clb[(size_t)rr * N + cc] = f2h(acc[rt][ct][j]);
          else      Crb[(size_t)rr * N + cc] = f2h(acc[rt][ct][j]);
        }
      }
    }
  }
}

// ---------------- CSR build: histogram -> multi-block scan -> scatter
__global__ void hist_kernel(const int* __restrict__ dsts, int* __restrict__ curs) {
  int i = blockIdx.x * blockDim.x + threadIdx.x;
  if (i >= ET) return;
  int d = (i < N_EDGES) ? dsts[i] : i - N_EDGES;
  atomicAdd(&curs[d], 1);
}

__global__ __launch_bounds__(256) void scan_part(
    const int* __restrict__ curs, int* __restrict__ rows, int* __restrict__ bsum)
{
  __shared__ int tmp[256];
  int t = threadIdx.x;
  int i = blockIdx.x * 256 + t;
  int v = (i < N_NODES) ? curs[i] : 0;
  tmp[t] = v;
  __syncthreads();
  #pragma unroll
  for (int off = 1; off < 256; off <<= 1) {
    int u = (t >= off) ? tmp[t - off] : 0;
    __syncthreads();
    tmp[t] += u;
    __syncthreads();
  }
  if (i < N_NODES) rows[i] = tmp[t] - v;
  if (t == 255) bsum[blockIdx.x] = tmp[255];
}

__global__ __launch_bounds__(256) void scan_bsums(
    const int* __restrict__ bsum, int* __restrict__ boff)
{
  __shared__ int tmp[256];
  int t = threadIdx.x;
  int v = (t < SCAN_BLOCKS) ? bsum[t] : 0;
  tmp[t] = v;
  __syncthreads();
  #pragma unroll
  for (int off = 1; off < 256; off <<= 1) {
    int u = (t >= off) ? tmp[t - off] : 0;
    __syncthreads();
    tmp[t] += u;
    __syncthreads();
  }
  if (t < SCAN_BLOCKS) boff[t] = tmp[t] - v;
}

__global__ __launch_bounds__(256) void scan_apply(
    int* __restrict__ rows, const int* __restrict__ boff, int* __restrict__ curs)
{
  int i = blockIdx.x * 256 + threadIdx.x;
  if (i < N_NODES) {
    int r = rows[i] + boff[blockIdx.x];
    rows[i] = r;
    curs[i] = r;
  }
  if (i == 0) rows[N_NODES] = ET;
}

__global__ void scatter_kernel(const int* __restrict__ srcs, const int* __restrict__ dsts,
                               int* __restrict__ curs, int* __restrict__ esrc) {
  int i = blockIdx.x * blockDim.x + threadIdx.x;
  if (i >= ET) return;
  int s, d;
  if (i < N_EDGES) { s = srcs[i]; d = dsts[i]; } else { s = d = i - N_EDGES; }
  int pos = atomicAdd(&curs[d], 1);
  esrc[pos] = s;
}

// ---------------- flash pass, D=256 (4 heads): one wave per dst, packed-fp16
// score (pk_add/pk_max + v_dot2_f32_f16), perm+dot2 aggregation (fp32 acc),
// exp2 domain, defer-max, 4-edge unroll.
__global__ __launch_bounds__(256) void flash256(
    const ushort* __restrict__ xl, const ushort* __restrict__ xr,
    const float* __restrict__ att, const int* __restrict__ rows,
    const int* __restrict__ esrc, float* __restrict__ out)
{
  const int wave = threadIdx.x >> 6, lane = threadIdx.x & 63;
  const int d = blockIdx.x * 4 + wave;   // N_NODES % 4 == 0
  const unsigned lo4 = lane * 4;
  int beg = rows[d], end = rows[d + 1];
  uint2 urx = *(const uint2*)&xr[(size_t)d * 256 + lo4];
  h16x2 x01 = bc16(urx.x), x23 = bc16(urx.y);
  float4 w = *(const float4*)&att[lo4];
  h16x2 w01 = pkrtz(w.x * LOG2E, w.y * LOG2E);
  h16x2 w23 = pkrtz(w.z * LOG2E, w.w * LOG2E);
  const _Float16 c2 = (_Float16)0.2f;
  const h16x2 c02 = {c2, c2};
  auto score = [&](uint2 u) -> float {
    h16x2 v01 = bc16(u.x) + x01;
    h16x2 v23 = bc16(u.y) + x23;
    v01 = hmax2(v01, v01 * c02);
    v23 = hmax2(v23, v23 * c02);
    return fdot2f(v01, w01, fdot2f(v23, w23, 0.f));
  };
  float m = -INFINITY, s = 0.f;
  float a0 = 0.f, a1 = 0.f, a2 = 0.f, a3 = 0.f;
  int p = beg;
  for (; p + 4 <= end; p += 4) {
    int s1 = esrc[p], s2 = esrc[p + 1], s3 = esrc[p + 2], s4 = esrc[p + 3];
    uint2 u1 = *(const uint2*)&xl[((unsigned)s1 << 8) + lo4];
    uint2 u2 = *(const uint2*)&xl[((unsigned)s2 << 8) + lo4];
    uint2 u3 = *(const uint2*)&xl[((unsigned)s3 << 8) + lo4];
    uint2 u4 = *(const uint2*)&xl[((unsigned)s4 << 8) + lo4];
    float e1 = score(u1);
    float e2 = score(u2);
    float e3 = score(u3);
    float e4 = score(u4);
    e1 += __shfl_xor(e1, 1); e2 += __shfl_xor(e2, 1);
    e3 += __shfl_xor(e3, 1); e4 += __shfl_xor(e4, 1);
    e1 += __shfl_xor(e1, 2); e2 += __shfl_xor(e2, 2);
    e3 += __shfl_xor(e3, 2); e4 += __shfl_xor(e4, 2);
    e1 += __shfl_xor(e1, 4); e2 += __shfl_xor(e2, 4);
    e3 += __shfl_xor(e3, 4); e4 += __shfl_xor(e4, 4);
    e1 += __shfl_xor(e1, 8); e2 += __shfl_xor(e2, 8);
    e3 += __shfl_xor(e3, 8); e4 += __shfl_xor(e4, 8);
    float gm = fmaxf(fmaxf(e1, e2), fmaxf(e3, e4));
    float p1, p2, p3, p4;
    if (__all(gm <= m + 8.0f)) {        // defer-max: no rescale, p <= 2^8
      p1 = ex2(e1 - m);
      p2 = ex2(e2 - m);
      p3 = ex2(e3 - m);
      p4 = ex2(e4 - m);
    } else {
      float mn = fmaxf(m, gm);
      float f = ex2(m - mn);
      p1 = ex2(e1 - mn);
      p2 = ex2(e2 - mn);
      p3 = ex2(e3 - mn);
      p4 = ex2(e4 - mn);
      s *= f; a0 *= f; a1 *= f; a2 *= f; a3 *= f;
      m = mn;
    }
    s += (p1 + p2) + (p3 + p4);
    h16x2 p12 = pkrtz(p1, p2), p34 = pkrtz(p3, p4);
    a0 = fdot2f(p12, bc16(PAIR_LO(u1.x, u2.x)), a0);
    a0 = fdot2f(p34, bc16(PAIR_LO(u3.x, u4.x)), a0);
    a1 = fdot2f(p12, bc16(PAIR_HI(u1.x, u2.x)), a1);
    a1 = fdot2f(p34, bc16(PAIR_HI(u3.x, u4.x)), a1);
    a2 = fdot2f(p12, bc16(PAIR_LO(u1.y, u2.y)), a2);
    a2 = fdot2f(p34, bc16(PAIR_LO(u3.y, u4.y)), a2);
    a3 = fdot2f(p12, bc16(PAIR_HI(u1.y, u2.y)), a3);
    a3 = fdot2f(p34, bc16(PAIR_HI(u3.y, u4.y)), a3);
  }
  for (; p < end; ++p) {
    int s1 = esrc[p];
    uint2 u1 = *(const uint2*)&xl[((unsigned)s1 << 8) + lo4];
    float e1 = score(u1);
    e1 += __shfl_xor(e1, 1);
    e1 += __shfl_xor(e1, 2);
    e1 += __shfl_xor(e1, 4);
    e1 += __shfl_xor(e1, 8);
    float mn = fmaxf(m, e1);
    float f = ex2(m - mn);
    float p1 = ex2(e1 - mn);
    h16x2 b01 = bc16(u1.x), b23 = bc16(u1.y);
    s = fmaf(s, f, p1);
    a0 = fmaf(a0, f, p1 * (float)b01[0]);
    a1 = fmaf(a1, f, p1 * (float)b01[1]);
    a2 = fmaf(a2, f, p1 * (float)b23[0]);
    a3 = fmaf(a3, f, p1 * (float)b23[1]);
    m = mn;
  }
  float inv = 1.f / (s + 1e-16f);
  *(float4*)&out[(size_t)d * 256 + lo4] =
      make_float4(a0 * inv, a1 * inv, a2 * inv, a3 * inv);
}

// ---------------- flash pass, D=64 (1 head): 8 lanes per dst (8 ch each),
// 8 dsts/wave, packed-fp16 score + perm+dot2 aggregation.
__global__ __launch_bounds__(256) void flash64(
    const ushort* __restrict__ xl, const ushort* __restrict__ xr,
    const float* __restrict__ att, const int* __restrict__ rows,
    const int* __restrict__ esrc, float* __restrict__ out)
{
  const int wave = threadIdx.x >> 6, lane = threadIdx.x & 63;
  const int di = lane >> 3, sl = lane & 7;
  const int idx = blockIdx.x * 32 + wave * 8 + di;
  const bool valid = idx < N_NODES;
  const int d = valid ? idx : N_NODES - 1;
  const unsigned ch = sl * 8;
  uint4 uxr = *(const uint4*)&xr[(size_t)d * 64 + ch];
  float4 wa = *(const float4*)&att[ch];
  float4 wb = *(const float4*)&att[ch + 4];
  h16x2 x0 = bc16(uxr.x), x1 = bc16(uxr.y), x2 = bc16(uxr.z), x3 = bc16(uxr.w);
  h16x2 w0 = pkrtz(wa.x * LOG2E, wa.y * LOG2E);
  h16x2 w1 = pkrtz(wa.z * LOG2E, wa.w * LOG2E);
  h16x2 w2 = pkrtz(wb.x * LOG2E, wb.y * LOG2E);
  h16x2 w3 = pkrtz(wb.z * LOG2E, wb.w * LOG2E);
  const _Float16 c2 = (_Float16)0.2f;
  const h16x2 c02 = {c2, c2};
  int beg = rows[d], end = rows[d + 1];
  float m = -INFINITY, s = 0.f;
  float a0 = 0.f, a1 = 0.f, a2 = 0.f, a3 = 0.f;
  float a4 = 0.f, a5 = 0.f, a6 = 0.f, a7 = 0.f;

  auto score = [&](uint4 u) -> float {
    h16x2 v0 = bc16(u.x) + x0;
    h16x2 v1 = bc16(u.y) + x1;
    h16x2 v2 = bc16(u.z) + x2;
    h16x2 v3 = bc16(u.w) + x3;
    v0 = hmax2(v0, v0 * c02);
    v1 = hmax2(v1, v1 * c02);
    v2 = hmax2(v2, v2 * c02);
    v3 = hmax2(v3, v3 * c02);
    return fdot2f(v0, w0, fdot2f(v1, w1, fdot2f(v2, w2, fdot2f(v3, w3, 0.f))));
  };
  auto one_edge = [&](int src) {
    uint4 u = *(const uint4*)&xl[((unsigned)src << 6) + ch];
    float e = score(u);
    e += __shfl_xor(e, 1);
    e += __shfl_xor(e, 2);
    e += __shfl_xor(e, 4);
    float mn = fmaxf(m, e);
    float f = ex2(m - mn);
    float pe = ex2(e - mn);
    h16x2 b0 = bc16(u.x), b1 = bc16(u.y), b2 = bc16(u.z), b3 = bc16(u.w);
    s = s * f + pe;
    a0 = fmaf(a0, f, pe * (float)b0[0]);
    a1 = fmaf(a1, f, pe * (float)b0[1]);
    a2 = fmaf(a2, f, pe * (float)b1[0]);
    a3 = fmaf(a3, f, pe * (float)b1[1]);
    a4 = fmaf(a4, f, pe * (float)b2[0]);
    a5 = fmaf(a5, f, pe * (float)b2[1]);
    a6 = fmaf(a6, f, pe * (float)b3[0]);
    a7 = fmaf(a7, f, pe * (float)b3[1]);
    m = mn;
  };

  int p = beg;
  int hd = min(end, (beg + 3) & ~3);
  for (; p < hd; ++p) one_edge(esrc[p]);
  for (; p + 4 <= end; p += 4) {
    int4 sv = *(const int4*)&esrc[p];
    uint4 u1 = *(const uint4*)&xl[((unsigned)sv.x << 6) + ch];
    uint4 u2 = *(const uint4*)&xl[((unsigned)sv.y << 6) + ch];
    uint4 u3 = *(const uint4*)&xl[((unsigned)sv.z << 6) + ch];
    uint4 u4 = *(const uint4*)&xl[((unsigned)sv.w << 6) + ch];
    float e1 = score(u1);
    float e2 = score(u2);
    float e3 = score(u3);
    float e4 = score(u4);
    e1 += __shfl_xor(e1, 1); e2 += __shfl_xor(e2, 1);
    e3 += __shfl_xor(e3, 1); e4 += __shfl_xor(e4, 1);
    e1 += __shfl_xor(e1, 2); e2 += __shfl_xor(e2, 2);
    e3 += __shfl_xor(e3, 2); e4 += __shfl_xor(e4, 2);
    e1 += __shfl_xor(e1, 4); e2 += __shfl_xor(e2, 4);
    e3 += __shfl_xor(e3, 4); e4 += __shfl_xor(e4, 4);
    float gm = fmaxf(fmaxf(e1, e2), fmaxf(e3, e4));
    float p1, p2, p3, p4;
    if (__all(gm <= m + 8.0f)) {
      p1 = ex2(e1 - m);
      p2 = ex2(e2 - m);
      p3 = ex2(e3 - m);
      p4 = ex2(e4 - m);
    } else {
      float mn = fmaxf(m, gm);
      float f = ex2(m - mn);
      p1 = ex2(e1 - mn);
      p2 = ex2(e2 - mn);
      p3 = ex2(e3 - mn);
      p4 = ex2(e4 - mn);
      s *= f;
      a0 *= f; a1 *= f; a2 *= f; a3 *= f;
      a4 *= f; a5 *= f; a6 *= f; a7 *= f;
      m = mn;
    }
    s += (p1 + p2) + (p3 + p4);
    h16x2 p12 = pkrtz(p1, p2), p34 = pkrtz(p3, p4);
    a0 = fdot2f(p12, bc16(PAIR_LO(u1.x, u2.x)), a0);
    a0 = fdot2f(p34, bc16(PAIR_LO(u3.x, u4.x)), a0);
    a1 = fdot2f(p12, bc16(PAIR_HI(u1.x, u2.x)), a1);
    a1 = fdot2f(p34, bc16(PAIR_HI(u3.x, u4.x)), a1);
    a2 = fdot2f(p12, bc16(PAIR_LO(u1.y, u2.y)), a2);
    a2 = fdot2f(p34, bc16(PAIR_LO(u3.y, u4.y)), a2);
    a3 = fdot2f(p12, bc16(PAIR_HI(u1.y, u2.y)), a3);
    a3 = fdot2f(p34, bc16(PAIR_HI(u3.y, u4.y)), a3);
    a4 = fdot2f(p12, bc16(PAIR_LO(u1.z, u2.z)), a4);
    a4 = fdot2f(p34, bc16(PAIR_LO(u3.z, u4.z)), a4);
    a5 = fdot2f(p12, bc16(PAIR_HI(u1.z, u2.z)), a5);
    a5 = fdot2f(p34, bc16(PAIR_HI(u3.z, u4.z)), a5);
    a6 = fdot2f(p12, bc16(PAIR_LO(u1.w, u2.w)), a6);
    a6 = fdot2f(p34, bc16(PAIR_LO(u3.w, u4.w)), a6);
    a7 = fdot2f(p12, bc16(PAIR_HI(u1.w, u2.w)), a7);
    a7 = fdot2f(p34, bc16(PAIR_HI(u3.w, u4.w)), a7);
  }
  for (; p < end; ++p) one_edge(esrc[p]);

  if (valid) {
    float inv = 1.f / (s + 1e-16f);
    *(float4*)&out[(size_t)d * 64 + ch] =
        make_float4(a0 * inv, a1 * inv, a2 * inv, a3 * inv);
    *(float4*)&out[(size_t)d * 64 + ch + 4] =
        make_float4(a4 * inv, a5 * inv, a6 * inv, a7 * inv);
  }
}

// ---------------- BN statistics (per-channel sum / sumsq)
template<int D_, int RPB>
__global__ __launch_bounds__(256) void bn_stats(const float* __restrict__ h,
    float* __restrict__ gsum, float* __restrict__ gsumsq, int nrows)
{
  constexpr int RG = 256 / D_;
  int c = threadIdx.x % D_;
  int rg = threadIdx.x / D_;
  int r0 = blockIdx.x * RPB;
  float s = 0.f, sq = 0.f;
  int rend = min(r0 + RPB, nrows);
  for (int r = r0 + rg; r < rend; r += RG) {
    float v = h[(size_t)r * D_ + c];
    s += v;
    sq = fmaf(v, v, sq);
  }
  atomicAdd(&gsum[c], s);
  atomicAdd(&gsumsq[c], sq);
}

// ---------------- fused pooling (BN finalize+apply inline) + classifier MLP.
__global__ __launch_bounds__(256) void pool_mlp(
    const float* __restrict__ h3, const int* __restrict__ batch,
    const float* __restrict__ gsum, const float* __restrict__ gsumsq,
    const float* __restrict__ g3, const float* __restrict__ be3,
    const float* __restrict__ Wc1, const float* __restrict__ bc1,
    const float* __restrict__ Wc2, const float* __restrict__ bc2,
    float* __restrict__ outp)
{
  int g = blockIdx.x;
  int t = threadIdx.x;
  int lane = t & 63, w = t >> 6;
  int lo, hi;
  {
    int a = 0, b = N_NODES;
    while (a < b) { int mid = (a + b) >> 1; if (batch[mid] < g) a = mid + 1; else b = mid; }
    lo = a;
    b = N_NODES;
    while (a < b) { int mid = (a + b) >> 1; if (batch[mid] < g + 1) a = mid + 1; else b = mid; }
    hi = a;
  }
  const float invn = 1.0f / (float)N_NODES;
  float mu = gsum[lane] * invn;
  float var = gsumsq[lane] * invn - mu * mu;
  float scl = g3[lane] * rsqrtf(var + 1e-5f);
  float shf = be3[lane] - mu * scl;
  float s = 0.f, mx = -INFINITY;
  for (int r = lo + w; r < hi; r += 4) {
    float v = fmaf(h3[(size_t)r * 64 + lane], scl, shf);
    s += v;
    mx = fmaxf(mx, v);
  }
  __shared__ float ssum[4][64];
  __shared__ float smax[4][64];
  __shared__ float pooled[128];
  ssum[w][lane] = s;
  smax[w][lane] = mx;
  __syncthreads();
  if (w == 0) {
    float tot = ssum[0][lane] + ssum[1][lane] + ssum[2][lane] + ssum[3][lane];
    float m4 = fmaxf(fmaxf(smax[0][lane], smax[1][lane]),
                     fmaxf(smax[2][lane], smax[3][lane]));
    float cnt = (float)(hi - lo);
    pooled[lane] = tot / fmaxf(cnt, 1.f);
    pooled[64 + lane] = m4;
  }
  __syncthreads();
  if (w == 0) {
    float a = bc1[lane];
    #pragma unroll 8
    for (int k = 0; k < 128; ++k) a = fmaf(pooled[k], Wc1[k * 64 + lane], a);
    a = fmaxf(a, 0.f);
    float v = a * Wc2[lane];
    v += __shfl_xor(v, 1);
    v += __shfl_xor(v, 2);
    v += __shfl_xor(v, 4);
    v += __shfl_xor(v, 8);
    v += __shfl_xor(v, 16);
    v += __shfl_xor(v, 32);
    if (lane == 0) outp[g] = v + bc2[0];
  }
}

extern "C" void kernel_launch(void* const* d_in, const int* in_sizes, int n_in,
                              void* d_out, int out_size, void* d_ws, size_t ws_size,
                              hipStream_t stream)
{
  const float* x    = (const float*)d_in[0];
  const int*   ei   = (const int*)d_in[1];
  const int*   batch= (const int*)d_in[2];
  const float* Wl1  = (const float*)d_in[3];
  const float* Wr1  = (const float*)d_in[4];
  const float* att1 = (const float*)d_in[5];
  // b1/b2/b3 cancel in the following BatchNorm -> unused
  const float* g1   = (const float*)d_in[7];
  const float* be1  = (const float*)d_in[8];
  const float* Wl2  = (const float*)d_in[9];
  const float* Wr2  = (const float*)d_in[10];
  const float* att2 = (const float*)d_in[11];
  const float* g2   = (const float*)d_in[13];
  const float* be2  = (const float*)d_in[14];
  const float* Wl3  = (const float*)d_in[15];
  const float* Wr3  = (const float*)d_in[16];
  const float* att3 = (const float*)d_in[17];
  const float* g3   = (const float*)d_in[19];
  const float* be3  = (const float*)d_in[20];
  const float* Wc1  = (const float*)d_in[21];
  const float* bc1  = (const float*)d_in[22];
  const float* Wc2  = (const float*)d_in[23];
  const float* bc2  = (const float*)d_in[24];

  const int* srcs = ei;
  const int* dsts = ei + N_EDGES;

  float* ws = (float*)d_ws;
  size_t o = 0;
  ushort* XLB = (ushort*)(ws + o); o += (size_t)N_NODES * HIDD / 2;  // fp16 xl
  ushort* XRB = (ushort*)(ws + o); o += (size_t)N_NODES * HIDD / 2;  // fp16 xr
  float* Hb = ws + o;            o += (size_t)N_NODES * HIDD;
  ushort* BT2 = (ushort*)(ws + o); o += (size_t)4 * 32 * 256 * 8 / 2;   // 2 mats x 2 halves
  ushort* BT3 = (ushort*)(ws + o); o += (size_t)4 * 32 * 64 * 8 / 2;
  int* ESRC = (int*)(ws + o);    o += ET;
  int* ROWS = (int*)(ws + o);    o += N_NODES + 1;
  int* CURS = (int*)(ws + o);    o += N_NODES;
  int* BSUM = (int*)(ws + o);    o += SCAN_BLOCKS;
  int* BOFF = (int*)(ws + o);    o += SCAN_BLOCKS;
  float* GS  = ws + o;           o += 256;
  float* GSQ = ws + o;           o += 256;

  const int ROW_BLOCKS = (N_NODES + 63) / 64;
  const int ROW_BLOCKS32 = (N_NODES + 31) / 32;
  const int DST_BLOCKS = (N_NODES + 3) / 4;
  constexpr int PLANE2 = 32 * 256 * 8;
  constexpr int PLANE3 = 32 * 64 * 8;

  // ================= weight transpose/split (independent; run once up front)
  convertB<256, 256><<<(65536 + 255) / 256, 256, 0, stream>>>(Wl2, BT2);
  convertB<256, 256><<<(65536 + 255) / 256, 256, 0, stream>>>(Wr2, BT2 + 2 * PLANE2);
  convertB<256, 64><<<(16384 + 255) / 256, 256, 0, stream>>>(Wl3, BT3);
  convertB<256, 64><<<(16384 + 255) / 256, 256, 0, stream>>>(Wr3, BT3 + 2 * PLANE3);

  // ================= CSR build (reused by all 3 layers) =================
  hipMemsetAsync(CURS, 0, N_NODES * 4, stream);
  hist_kernel<<<(ET + 255) / 256, 256, 0, stream>>>(dsts, CURS);
  scan_part<<<SCAN_BLOCKS, 256, 0, stream>>>(CURS, ROWS, BSUM);
  scan_bsums<<<1, 256, 0, stream>>>(BSUM, BOFF);
  scan_apply<<<SCAN_BLOCKS, 256, 0, stream>>>(ROWS, BOFF, CURS);
  scatter_kernel<<<(ET + 255) / 256, 256, 0, stream>>>(srcs, dsts, CURS, ESRC);

  // ================= layer 1 (16 -> 4x64, concat): fp32 vector GEMM ======
  gemm_dual<16, 256><<<dim3(ROW_BLOCKS, 4), 256, 0, stream>>>(
      x, Wl1, Wr1, XLB, XRB, N_NODES);
  flash256<<<DST_BLOCKS, 256, 0, stream>>>(XLB, XRB, att1, ROWS, ESRC, Hb);
  hipMemsetAsync(GS, 0, 512 * 4, stream);
  bn_stats<256, 64><<<ROW_BLOCKS, 256, 0, stream>>>(Hb, GS, GSQ, N_NODES);

  // ================= layer 2 (256 -> 4x64): fully-fused BN+ELU+MFMA GEMM ==
  gemm_fused<256><<<ROW_BLOCKS32, 512, 0, stream>>>(
      Hb, GS, GSQ, g1, be1, BT2, XLB, XRB);
  flash256<<<DST_BLOCKS, 256, 0, stream>>>(XLB, XRB, att2, ROWS, ESRC, Hb);
  hipMemsetAsync(GS, 0, 512 * 4, stream);
  bn_stats<256, 64><<<ROW_BLOCKS, 256, 0, stream>>>(Hb, GS, GSQ, N_NODES);

  // ================= layer 3 (256 -> 64, 1 head): fused MFMA GEMM ========
  gemm_fused<64><<<ROW_BLOCKS32, 128, 0, stream>>>(
      Hb, GS, GSQ, g2, be2, BT3, XLB, XRB);
  flash64<<<(N_NODES + 31) / 32, 256, 0, stream>>>(XLB, XRB, att3, ROWS, ESRC, Hb);
  hipMemsetAsync(GS, 0, 512 * 4, stream);
  bn_stats<64, 256><<<(N_NODES + 255) / 256, 256, 0, stream>>>(Hb, GS, GSQ, N_NODES);

  // ================= fused pooling (BN inline) + classifier ==============
  pool_mlp<<<N_GRAPHS, 256, 0, stream>>>(Hb, batch, GS, GSQ, g3, be3,
                                         Wc1, bc1, Wc2, bc2, (float*)d_out);
}

// Round 15
// 518.892 us; speedup vs baseline: 1.5452x; 1.0223x over previous
//
#include <hip/hip_runtime.h>
#include <math.h>

#define N_NODES 50000
#define N_EDGES 800000
#define ET (N_EDGES + N_NODES)
#define N_GRAPHS 200
#define F_INN 16
#define C_DIM 64
#define N_HEADS 4
#define HIDD 256
#define SCAN_BLOCKS ((N_NODES + 255) / 256)

typedef __attribute__((ext_vector_type(8))) short short8;
typedef __attribute__((ext_vector_type(8))) ushort ushort8;
typedef __attribute__((ext_vector_type(4))) float f32x4;
typedef __attribute__((ext_vector_type(2))) float f32x2;
typedef __attribute__((ext_vector_type(2))) _Float16 h16x2;

#define LOG2E 1.44269504088896340736f

__device__ __forceinline__ float ex2(float x) {
#if __has_builtin(__builtin_amdgcn_exp2f)
  return __builtin_amdgcn_exp2f(x);
#else
  return exp2f(x);
#endif
}

__device__ __forceinline__ h16x2 bc16(unsigned u) {
  union { unsigned u; h16x2 h; } c; c.u = u; return c.h;
}
__device__ __forceinline__ ushort f2h(float f) {
  union { _Float16 h; ushort u; } c; c.h = (_Float16)f; return c.u;
}
__device__ __forceinline__ float h2f(ushort u) {
  union { ushort u; _Float16 h; } c; c.u = u; return (float)c.h;
}

#if __has_builtin(__builtin_amdgcn_cvt_pkrtz)
using hw2 = decltype(__builtin_amdgcn_cvt_pkrtz(0.f, 0.f));
__device__ __forceinline__ h16x2 pkrtz(float a, float b) {
  union { hw2 w; h16x2 h; } c;
  c.w = __builtin_amdgcn_cvt_pkrtz(a, b);
  return c.h;
}
#else
__device__ __forceinline__ h16x2 pkrtz(float a, float b) {
  h16x2 r; r[0] = (_Float16)a; r[1] = (_Float16)b; return r;
}
#endif

__device__ __forceinline__ float fdot2f(h16x2 a, h16x2 b, float c) {
#if __has_builtin(__builtin_amdgcn_fdot2) && __has_builtin(__builtin_amdgcn_cvt_pkrtz)
  union { h16x2 h; hw2 w; } ca, cb;
  ca.h = a; cb.h = b;
  return __builtin_amdgcn_fdot2(ca.w, cb.w, c, false);
#else
  return (float)a[0] * (float)b[0] + (float)a[1] * (float)b[1] + c;
#endif
}
__device__ __forceinline__ h16x2 hmax2(h16x2 a, h16x2 b) {
#if __has_builtin(__builtin_elementwise_max)
  return __builtin_elementwise_max(a, b);
#else
  h16x2 r; r[0] = a[0] > b[0] ? a[0] : b[0]; r[1] = a[1] > b[1] ? a[1] : b[1]; return r;
#endif
}
__device__ __forceinline__ unsigned permu(unsigned s0, unsigned s1, unsigned sel) {
#if __has_builtin(__builtin_amdgcn_perm)
  return __builtin_amdgcn_perm(s0, s1, sel);
#else
  unsigned long long cat = (((unsigned long long)s0) << 32) | s1;
  unsigned r = 0;
  for (int i = 0; i < 4; ++i) {
    unsigned b = (sel >> (8 * i)) & 0xff;
    r |= ((unsigned)((cat >> (8 * (b & 7))) & 0xff)) << (8 * i);
  }
  return r;
#endif
}
// pair_lo(A,B) -> (A.low16, B.low16) ; pair_hi -> (A.high16, B.high16)
#define PAIR_LO(A, B) permu((B), (A), 0x05040100u)
#define PAIR_HI(A, B) permu((B), (A), 0x07060302u)

// ---------------- dual GEMM (fp32 vector path, layer 1 only: K=16)
// Both outputs written fp16 (Cl feeds gathers, Cr feeds scores).
template<int K, int M>
__global__ __launch_bounds__(256) void gemm_dual(
    const float* __restrict__ A, const float* __restrict__ Bl,
    const float* __restrict__ Br, ushort* __restrict__ Clb,
    ushort* __restrict__ Crb, int nrows)
{
  __shared__ __align__(16) float As[16][64];
  __shared__ __align__(16) float Bls[16][64];
  __shared__ __align__(16) float Brs[16][64];
  int tid = threadIdx.x;
  int row0 = blockIdx.x * 64;
  int col0 = blockIdx.y * 64;
  int tr = (tid >> 4) << 2;
  int tc = (tid & 15) << 2;
  float accL[4][4] = {{0.f}}, accR[4][4] = {{0.f}};
  int arow = tid >> 2, ak = (tid & 3) << 2;
  int brow = tid >> 4, bcol = (tid & 15) << 2;
  for (int k0 = 0; k0 < K; k0 += 16) {
    float4 av = make_float4(0.f, 0.f, 0.f, 0.f);
    int gr = row0 + arow;
    if (gr < nrows) av = *(const float4*)&A[(size_t)gr * K + k0 + ak];
    As[ak + 0][arow] = av.x;
    As[ak + 1][arow] = av.y;
    As[ak + 2][arow] = av.z;
    As[ak + 3][arow] = av.w;
    *(float4*)&Bls[brow][bcol] = *(const float4*)&Bl[(size_t)(k0 + brow) * M + col0 + bcol];
    *(float4*)&Brs[brow][bcol] = *(const float4*)&Br[(size_t)(k0 + brow) * M + col0 + bcol];
    __syncthreads();
    #pragma unroll
    for (int k = 0; k < 16; ++k) {
      float4 a = *(const float4*)&As[k][tr];
      float4 bl = *(const float4*)&Bls[k][tc];
      float4 br = *(const float4*)&Brs[k][tc];
      float aa[4] = {a.x, a.y, a.z, a.w};
      float lb[4] = {bl.x, bl.y, bl.z, bl.w};
      float rb[4] = {br.x, br.y, br.z, br.w};
      #pragma unroll
      for (int ii = 0; ii < 4; ++ii)
        #pragma unroll
        for (int jj = 0; jj < 4; ++jj) {
          accL[ii][jj] = fmaf(aa[ii], lb[jj], accL[ii][jj]);
          accR[ii][jj] = fmaf(aa[ii], rb[jj], accR[ii][jj]);
        }
    }
    __syncthreads();
  }
  #pragma unroll
  for (int ii = 0; ii < 4; ++ii) {
    int gr = row0 + tr + ii;
    if (gr < nrows) {
      *(ushort4*)&Clb[(size_t)gr * M + col0 + tc] =
          make_ushort4(f2h(accL[ii][0]), f2h(accL[ii][1]),
                       f2h(accL[ii][2]), f2h(accL[ii][3]));
      *(ushort4*)&Crb[(size_t)gr * M + col0 + tc] =
          make_ushort4(f2h(accR[ii][0]), f2h(accR[ii][1]),
                       f2h(accR[ii][2]), f2h(accR[ii][3]));
    }
  }
}

// ---------------- bf16x2 split helpers (GEMM inputs stay bf16x2-split)
__device__ __forceinline__ void split_bf16(float a, ushort& hi, ushort& lo) {
  unsigned u = __float_as_uint(a);
  hi = (ushort)(u >> 16);
  float ah = __uint_as_float(u & 0xffff0000u);
  float r = a - ah;                      // exact
  lo = (ushort)(__float_as_uint(r) >> 16);
}

// ---------------- convert a weight matrix [K][N] -> [half][K/8][N][8] bf16
template<int K, int N>
__global__ void convertB(const float* __restrict__ W, ushort* __restrict__ BTmat) {
  int idx = blockIdx.x * blockDim.x + threadIdx.x;
  if (idx >= K * N) return;
  int k = idx / N, n = idx - k * N;
  ushort hi, lo;
  split_bf16(W[idx], hi, lo);
  size_t dst = ((size_t)(k >> 3) * N + n) * 8 + (k & 7);
  BTmat[dst] = hi;
  BTmat[(size_t)(K / 8) * N * 8 + dst] = lo;
}

// ---------------- fully-fused MFMA dual GEMM (K=256), BM=32 rows/block:
//   H is fp16; A' = elu(bn(H)) split to bf16 hi/lo, staged in LDS (swizzled).
//   Outputs written fp16.
template<int N>
__global__ __launch_bounds__(N * 2) void gemm_fused(
    const ushort* __restrict__ H, const float* __restrict__ gsum,
    const float* __restrict__ gsumsq, const float* __restrict__ g,
    const float* __restrict__ be, const ushort* __restrict__ BT,
    ushort* __restrict__ Clb, ushort* __restrict__ Crb)
{
  constexpr int THREADS = N * 2;
  constexpr int PLANE = 32 * N * 8;
  __shared__ float SCs[256], SHs[256];
  __shared__ ushort Ah_s[32 * 256];
  __shared__ ushort Al_s[32 * 256];
  const int tid = threadIdx.x;
  const int brow0 = blockIdx.x * 32;

  // phase 0: BN finalize in-block
  const float invn = 1.0f / (float)N_NODES;
  for (int c = tid; c < 256; c += THREADS) {
    float mu = gsum[c] * invn;
    float var = gsumsq[c] * invn - mu * mu;
    float sc = g[c] * rsqrtf(var + 1e-5f);
    SCs[c] = sc;
    SHs[c] = be[c] - mu * sc;
  }
  __syncthreads();

  // phase 1: stage 32-row A tile -> LDS, BN+ELU+bf16x2 split; XOR swizzle.
  for (int gid = tid; gid < 1024; gid += THREADS) {
    int r = gid >> 5;
    int ch0 = (gid & 31) * 8;
    int grow = min(brow0 + r, N_NODES - 1);
    uint4 hv = *(const uint4*)&H[(size_t)grow * 256 + ch0];
    h16x2 q0 = bc16(hv.x), q1 = bc16(hv.y), q2 = bc16(hv.z), q3 = bc16(hv.w);
    float4 sc0 = *(const float4*)&SCs[ch0];
    float4 sc1 = *(const float4*)&SCs[ch0 + 4];
    float4 sh0 = *(const float4*)&SHs[ch0];
    float4 sh1 = *(const float4*)&SHs[ch0 + 4];
    float vv[8] = {(float)q0[0], (float)q0[1], (float)q1[0], (float)q1[1],
                   (float)q2[0], (float)q2[1], (float)q3[0], (float)q3[1]};
    float scv[8] = {sc0.x, sc0.y, sc0.z, sc0.w, sc1.x, sc1.y, sc1.z, sc1.w};
    float shv[8] = {sh0.x, sh0.y, sh0.z, sh0.w, sh1.x, sh1.y, sh1.z, sh1.w};
    short8 hi8, lo8;
    #pragma unroll
    for (int j = 0; j < 8; ++j) {
      float t = fmaf(vv[j], scv[j], shv[j]);
      float e = t > 0.f ? t : __expf(t) - 1.f;
      ushort h, l;
      split_bf16(e, h, l);
      hi8[j] = (short)h;
      lo8[j] = (short)l;
    }
    int off = r * 512 + ((ch0 * 2) ^ ((r & 7) << 4));
    *(short8*)((char*)Ah_s + off) = hi8;
    *(short8*)((char*)Al_s + off) = lo8;
  }
  __syncthreads();

  // phase 2: k-loop. wave -> 64 combined cols (mat = L if combc<N else R).
  const int wave = tid >> 6, lane = tid & 63;
  const int cn = lane & 15, kgrp = lane >> 4;
  const int combc = wave * 64;
  const bool isR = combc >= N;
  const ushort* Bh = BT + (isR ? 2 * PLANE : 0);
  const ushort* Bl_ = Bh + PLANE;
  const int cb = combc & (N - 1);
  f32x4 acc[2][4];
  #pragma unroll
  for (int rt = 0; rt < 2; ++rt)
    #pragma unroll
    for (int ct = 0; ct < 4; ++ct) acc[rt][ct] = (f32x4)(0.f);

  #pragma unroll 2
  for (int k0 = 0; k0 < 256; k0 += 32) {
    short8 ah[2], al[2];
    #pragma unroll
    for (int rt = 0; rt < 2; ++rt) {
      int row = rt * 16 + cn;
      int off = row * 512 + (((k0 * 2) + kgrp * 16) ^ ((row & 7) << 4));
      ah[rt] = *(const short8*)((const char*)Ah_s + off);
      al[rt] = *(const short8*)((const char*)Al_s + off);
    }
    const size_t bbase = (size_t)((k0 >> 3) + kgrp) * (N * 8);
    #pragma unroll
    for (int ct = 0; ct < 4; ++ct) {
      const size_t bo = bbase + (size_t)(cb + ct * 16 + cn) * 8;
      short8 bh = *(const short8*)&Bh[bo];
      short8 bl = *(const short8*)&Bl_[bo];
      #pragma unroll
      for (int rt = 0; rt < 2; ++rt) {
        acc[rt][ct] = __builtin_amdgcn_mfma_f32_16x16x32_bf16(ah[rt], bh, acc[rt][ct], 0, 0, 0);
        acc[rt][ct] = __builtin_amdgcn_mfma_f32_16x16x32_bf16(ah[rt], bl, acc[rt][ct], 0, 0, 0);
        acc[rt][ct] = __builtin_amdgcn_mfma_f32_16x16x32_bf16(al[rt], bh, acc[rt][ct], 0, 0, 0);
      }
    }
  }

  // epilogue: C/D layout col=lane&15, row=(lane>>4)*4+reg  [m89 verified]
  #pragma unroll
  for (int ct = 0; ct < 4; ++ct) {
    int cc = cb + ct * 16 + cn;
    #pragma unroll
    for (int rt = 0; rt < 2; ++rt) {
      int crow0 = brow0 + rt * 16 + kgrp * 4;
      #pragma unroll
      for (int j = 0; j < 4; ++j) {
        int rr = crow0 + j;
        if (rr < N_NODES) {
          if (!isR) Clb[(size_t)rr * N + cc] = f2h(acc[rt][ct][j]);
          else      Crb[(size_t)rr * N + cc] = f2h(acc[rt][ct][j]);
        }
      }
    }
  }
}

// ---------------- CSR build: histogram -> multi-block scan -> scatter
__global__ void hist_kernel(const int* __restrict__ dsts, int* __restrict__ curs) {
  int i = blockIdx.x * blockDim.x + threadIdx.x;
  if (i >= ET) return;
  int d = (i < N_EDGES) ? dsts[i] : i - N_EDGES;
  atomicAdd(&curs[d], 1);
}

__global__ __launch_bounds__(256) void scan_part(
    const int* __restrict__ curs, int* __restrict__ rows, int* __restrict__ bsum)
{
  __shared__ int tmp[256];
  int t = threadIdx.x;
  int i = blockIdx.x * 256 + t;
  int v = (i < N_NODES) ? curs[i] : 0;
  tmp[t] = v;
  __syncthreads();
  #pragma unroll
  for (int off = 1; off < 256; off <<= 1) {
    int u = (t >= off) ? tmp[t - off] : 0;
    __syncthreads();
    tmp[t] += u;
    __syncthreads();
  }
  if (i < N_NODES) rows[i] = tmp[t] - v;
  if (t == 255) bsum[blockIdx.x] = tmp[255];
}

__global__ __launch_bounds__(256) void scan_bsums(
    const int* __restrict__ bsum, int* __restrict__ boff)
{
  __shared__ int tmp[256];
  int t = threadIdx.x;
  int v = (t < SCAN_BLOCKS) ? bsum[t] : 0;
  tmp[t] = v;
  __syncthreads();
  #pragma unroll
  for (int off = 1; off < 256; off <<= 1) {
    int u = (t >= off) ? tmp[t - off] : 0;
    __syncthreads();
    tmp[t] += u;
    __syncthreads();
  }
  if (t < SCAN_BLOCKS) boff[t] = tmp[t] - v;
}

__global__ __launch_bounds__(256) void scan_apply(
    int* __restrict__ rows, const int* __restrict__ boff, int* __restrict__ curs)
{
  int i = blockIdx.x * 256 + threadIdx.x;
  if (i < N_NODES) {
    int r = rows[i] + boff[blockIdx.x];
    rows[i] = r;
    curs[i] = r;
  }
  if (i == 0) rows[N_NODES] = ET;
}

__global__ void scatter_kernel(const int* __restrict__ srcs, const int* __restrict__ dsts,
                               int* __restrict__ curs, int* __restrict__ esrc) {
  int i = blockIdx.x * blockDim.x + threadIdx.x;
  if (i >= ET) return;
  int s, d;
  if (i < N_EDGES) { s = srcs[i]; d = dsts[i]; } else { s = d = i - N_EDGES; }
  int pos = atomicAdd(&curs[d], 1);
  esrc[pos] = s;
}

// ---------------- flash pass, D=256 (4 heads): one wave per dst, packed-fp16
// score + perm+dot2 aggregation (fp32 acc), exp2 domain, defer-max,
// 8-edge unroll (deep gather pipeline). Output fp16.
__global__ __launch_bounds__(256) void flash256(
    const ushort* __restrict__ xl, const ushort* __restrict__ xr,
    const float* __restrict__ att, const int* __restrict__ rows,
    const int* __restrict__ esrc, ushort* __restrict__ out)
{
  const int wave = threadIdx.x >> 6, lane = threadIdx.x & 63;
  const int d = blockIdx.x * 4 + wave;   // N_NODES % 4 == 0
  const unsigned lo4 = lane * 4;
  int beg = rows[d], end = rows[d + 1];
  uint2 urx = *(const uint2*)&xr[(size_t)d * 256 + lo4];
  h16x2 x01 = bc16(urx.x), x23 = bc16(urx.y);
  float4 w = *(const float4*)&att[lo4];
  h16x2 w01 = pkrtz(w.x * LOG2E, w.y * LOG2E);
  h16x2 w23 = pkrtz(w.z * LOG2E, w.w * LOG2E);
  const _Float16 c2 = (_Float16)0.2f;
  const h16x2 c02 = {c2, c2};
  auto score = [&](uint2 u) -> float {
    h16x2 v01 = bc16(u.x) + x01;
    h16x2 v23 = bc16(u.y) + x23;
    v01 = hmax2(v01, v01 * c02);
    v23 = hmax2(v23, v23 * c02);
    return fdot2f(v01, w01, fdot2f(v23, w23, 0.f));
  };
  float m = -INFINITY, s = 0.f;
  float a0 = 0.f, a1 = 0.f, a2 = 0.f, a3 = 0.f;
  int p = beg;
  for (; p + 8 <= end; p += 8) {
    uint2 u[8];
    float e[8];
    #pragma unroll
    for (int j = 0; j < 8; ++j) {
      int sj = esrc[p + j];
      u[j] = *(const uint2*)&xl[((unsigned)sj << 8) + lo4];
    }
    #pragma unroll
    for (int j = 0; j < 8; ++j) e[j] = score(u[j]);
    #pragma unroll
    for (int st = 1; st <= 8; st <<= 1) {
      #pragma unroll
      for (int j = 0; j < 8; ++j) e[j] += __shfl_xor(e[j], st);
    }
    float gm = e[0];
    #pragma unroll
    for (int j = 1; j < 8; ++j) gm = fmaxf(gm, e[j]);
    float pr[8];
    if (__all(gm <= m + 8.0f)) {        // defer-max: no rescale, p <= 2^8
      #pragma unroll
      for (int j = 0; j < 8; ++j) pr[j] = ex2(e[j] - m);
    } else {
      float mn = fmaxf(m, gm);
      float f = ex2(m - mn);
      #pragma unroll
      for (int j = 0; j < 8; ++j) pr[j] = ex2(e[j] - mn);
      s *= f; a0 *= f; a1 *= f; a2 *= f; a3 *= f;
      m = mn;
    }
    s += ((pr[0] + pr[1]) + (pr[2] + pr[3])) + ((pr[4] + pr[5]) + (pr[6] + pr[7]));
    h16x2 p01 = pkrtz(pr[0], pr[1]), p23 = pkrtz(pr[2], pr[3]);
    h16x2 p45 = pkrtz(pr[4], pr[5]), p67 = pkrtz(pr[6], pr[7]);
    a0 = fdot2f(p01, bc16(PAIR_LO(u[0].x, u[1].x)), a0);
    a0 = fdot2f(p23, bc16(PAIR_LO(u[2].x, u[3].x)), a0);
    a0 = fdot2f(p45, bc16(PAIR_LO(u[4].x, u[5].x)), a0);
    a0 = fdot2f(p67, bc16(PAIR_LO(u[6].x, u[7].x)), a0);
    a1 = fdot2f(p01, bc16(PAIR_HI(u[0].x, u[1].x)), a1);
    a1 = fdot2f(p23, bc16(PAIR_HI(u[2].x, u[3].x)), a1);
    a1 = fdot2f(p45, bc16(PAIR_HI(u[4].x, u[5].x)), a1);
    a1 = fdot2f(p67, bc16(PAIR_HI(u[6].x, u[7].x)), a1);
    a2 = fdot2f(p01, bc16(PAIR_LO(u[0].y, u[1].y)), a2);
    a2 = fdot2f(p23, bc16(PAIR_LO(u[2].y, u[3].y)), a2);
    a2 = fdot2f(p45, bc16(PAIR_LO(u[4].y, u[5].y)), a2);
    a2 = fdot2f(p67, bc16(PAIR_LO(u[6].y, u[7].y)), a2);
    a3 = fdot2f(p01, bc16(PAIR_HI(u[0].y, u[1].y)), a3);
    a3 = fdot2f(p23, bc16(PAIR_HI(u[2].y, u[3].y)), a3);
    a3 = fdot2f(p45, bc16(PAIR_HI(u[4].y, u[5].y)), a3);
    a3 = fdot2f(p67, bc16(PAIR_HI(u[6].y, u[7].y)), a3);
  }
  for (; p + 4 <= end; p += 4) {
    int s1 = esrc[p], s2 = esrc[p + 1], s3 = esrc[p + 2], s4 = esrc[p + 3];
    uint2 u1 = *(const uint2*)&xl[((unsigned)s1 << 8) + lo4];
    uint2 u2 = *(const uint2*)&xl[((unsigned)s2 << 8) + lo4];
    uint2 u3 = *(const uint2*)&xl[((unsigned)s3 << 8) + lo4];
    uint2 u4 = *(const uint2*)&xl[((unsigned)s4 << 8) + lo4];
    float e1 = score(u1);
    float e2 = score(u2);
    float e3 = score(u3);
    float e4 = score(u4);
    e1 += __shfl_xor(e1, 1); e2 += __shfl_xor(e2, 1);
    e3 += __shfl_xor(e3, 1); e4 += __shfl_xor(e4, 1);
    e1 += __shfl_xor(e1, 2); e2 += __shfl_xor(e2, 2);
    e3 += __shfl_xor(e3, 2); e4 += __shfl_xor(e4, 2);
    e1 += __shfl_xor(e1, 4); e2 += __shfl_xor(e2, 4);
    e3 += __shfl_xor(e3, 4); e4 += __shfl_xor(e4, 4);
    e1 += __shfl_xor(e1, 8); e2 += __shfl_xor(e2, 8);
    e3 += __shfl_xor(e3, 8); e4 += __shfl_xor(e4, 8);
    float gm = fmaxf(fmaxf(e1, e2), fmaxf(e3, e4));
    float p1, p2, p3, p4;
    if (__all(gm <= m + 8.0f)) {
      p1 = ex2(e1 - m);
      p2 = ex2(e2 - m);
      p3 = ex2(e3 - m);
      p4 = ex2(e4 - m);
    } else {
      float mn = fmaxf(m, gm);
      float f = ex2(m - mn);
      p1 = ex2(e1 - mn);
      p2 = ex2(e2 - mn);
      p3 = ex2(e3 - mn);
      p4 = ex2(e4 - mn);
      s *= f; a0 *= f; a1 *= f; a2 *= f; a3 *= f;
      m = mn;
    }
    s += (p1 + p2) + (p3 + p4);
    h16x2 p12 = pkrtz(p1, p2), p34 = pkrtz(p3, p4);
    a0 = fdot2f(p12, bc16(PAIR_LO(u1.x, u2.x)), a0);
    a0 = fdot2f(p34, bc16(PAIR_LO(u3.x, u4.x)), a0);
    a1 = fdot2f(p12, bc16(PAIR_HI(u1.x, u2.x)), a1);
    a1 = fdot2f(p34, bc16(PAIR_HI(u3.x, u4.x)), a1);
    a2 = fdot2f(p12, bc16(PAIR_LO(u1.y, u2.y)), a2);
    a2 = fdot2f(p34, bc16(PAIR_LO(u3.y, u4.y)), a2);
    a3 = fdot2f(p12, bc16(PAIR_HI(u1.y, u2.y)), a3);
    a3 = fdot2f(p34, bc16(PAIR_HI(u3.y, u4.y)), a3);
  }
  for (; p < end; ++p) {
    int s1 = esrc[p];
    uint2 u1 = *(const uint2*)&xl[((unsigned)s1 << 8) + lo4];
    float e1 = score(u1);
    e1 += __shfl_xor(e1, 1);
    e1 += __shfl_xor(e1, 2);
    e1 += __shfl_xor(e1, 4);
    e1 += __shfl_xor(e1, 8);
    float mn = fmaxf(m, e1);
    float f = ex2(m - mn);
    float p1 = ex2(e1 - mn);
    h16x2 b01 = bc16(u1.x), b23 = bc16(u1.y);
    s = fmaf(s, f, p1);
    a0 = fmaf(a0, f, p1 * (float)b01[0]);
    a1 = fmaf(a1, f, p1 * (float)b01[1]);
    a2 = fmaf(a2, f, p1 * (float)b23[0]);
    a3 = fmaf(a3, f, p1 * (float)b23[1]);
    m = mn;
  }
  float inv = 1.f / (s + 1e-16f);
  *(ushort4*)&out[(size_t)d * 256 + lo4] =
      make_ushort4(f2h(a0 * inv), f2h(a1 * inv), f2h(a2 * inv), f2h(a3 * inv));
}

// ---------------- flash pass, D=64 (1 head): 8 lanes per dst (8 ch each),
// 8 dsts/wave, packed-fp16 score + perm+dot2 aggregation. Output fp16.
__global__ __launch_bounds__(256) void flash64(
    const ushort* __restrict__ xl, const ushort* __restrict__ xr,
    const float* __restrict__ att, const int* __restrict__ rows,
    const int* __restrict__ esrc, ushort* __restrict__ out)
{
  const int wave = threadIdx.x >> 6, lane = threadIdx.x & 63;
  const int di = lane >> 3, sl = lane & 7;
  const int idx = blockIdx.x * 32 + wave * 8 + di;
  const bool valid = idx < N_NODES;
  const int d = valid ? idx : N_NODES - 1;
  const unsigned ch = sl * 8;
  uint4 uxr = *(const uint4*)&xr[(size_t)d * 64 + ch];
  float4 wa = *(const float4*)&att[ch];
  float4 wb = *(const float4*)&att[ch + 4];
  h16x2 x0 = bc16(uxr.x), x1 = bc16(uxr.y), x2 = bc16(uxr.z), x3 = bc16(uxr.w);
  h16x2 w0 = pkrtz(wa.x * LOG2E, wa.y * LOG2E);
  h16x2 w1 = pkrtz(wa.z * LOG2E, wa.w * LOG2E);
  h16x2 w2 = pkrtz(wb.x * LOG2E, wb.y * LOG2E);
  h16x2 w3 = pkrtz(wb.z * LOG2E, wb.w * LOG2E);
  const _Float16 c2 = (_Float16)0.2f;
  const h16x2 c02 = {c2, c2};
  int beg = rows[d], end = rows[d + 1];
  float m = -INFINITY, s = 0.f;
  float a0 = 0.f, a1 = 0.f, a2 = 0.f, a3 = 0.f;
  float a4 = 0.f, a5 = 0.f, a6 = 0.f, a7 = 0.f;

  auto score = [&](uint4 u) -> float {
    h16x2 v0 = bc16(u.x) + x0;
    h16x2 v1 = bc16(u.y) + x1;
    h16x2 v2 = bc16(u.z) + x2;
    h16x2 v3 = bc16(u.w) + x3;
    v0 = hmax2(v0, v0 * c02);
    v1 = hmax2(v1, v1 * c02);
    v2 = hmax2(v2, v2 * c02);
    v3 = hmax2(v3, v3 * c02);
    return fdot2f(v0, w0, fdot2f(v1, w1, fdot2f(v2, w2, fdot2f(v3, w3, 0.f))));
  };
  auto one_edge = [&](int src) {
    uint4 u = *(const uint4*)&xl[((unsigned)src << 6) + ch];
    float e = score(u);
    e += __shfl_xor(e, 1);
    e += __shfl_xor(e, 2);
    e += __shfl_xor(e, 4);
    float mn = fmaxf(m, e);
    float f = ex2(m - mn);
    float pe = ex2(e - mn);
    h16x2 b0 = bc16(u.x), b1 = bc16(u.y), b2 = bc16(u.z), b3 = bc16(u.w);
    s = s * f + pe;
    a0 = fmaf(a0, f, pe * (float)b0[0]);
    a1 = fmaf(a1, f, pe * (float)b0[1]);
    a2 = fmaf(a2, f, pe * (float)b1[0]);
    a3 = fmaf(a3, f, pe * (float)b1[1]);
    a4 = fmaf(a4, f, pe * (float)b2[0]);
    a5 = fmaf(a5, f, pe * (float)b2[1]);
    a6 = fmaf(a6, f, pe * (float)b3[0]);
    a7 = fmaf(a7, f, pe * (float)b3[1]);
    m = mn;
  };

  int p = beg;
  int hd = min(end, (beg + 3) & ~3);
  for (; p < hd; ++p) one_edge(esrc[p]);
  for (; p + 4 <= end; p += 4) {
    int4 sv = *(const int4*)&esrc[p];
    uint4 u1 = *(const uint4*)&xl[((unsigned)sv.x << 6) + ch];
    uint4 u2 = *(const uint4*)&xl[((unsigned)sv.y << 6) + ch];
    uint4 u3 = *(const uint4*)&xl[((unsigned)sv.z << 6) + ch];
    uint4 u4 = *(const uint4*)&xl[((unsigned)sv.w << 6) + ch];
    float e1 = score(u1);
    float e2 = score(u2);
    float e3 = score(u3);
    float e4 = score(u4);
    e1 += __shfl_xor(e1, 1); e2 += __shfl_xor(e2, 1);
    e3 += __shfl_xor(e3, 1); e4 += __shfl_xor(e4, 1);
    e1 += __shfl_xor(e1, 2); e2 += __shfl_xor(e2, 2);
    e3 += __shfl_xor(e3, 2); e4 += __shfl_xor(e4, 2);
    e1 += __shfl_xor(e1, 4); e2 += __shfl_xor(e2, 4);
    e3 += __shfl_xor(e3, 4); e4 += __shfl_xor(e4, 4);
    float gm = fmaxf(fmaxf(e1, e2), fmaxf(e3, e4));
    float p1, p2, p3, p4;
    if (__all(gm <= m + 8.0f)) {
      p1 = ex2(e1 - m);
      p2 = ex2(e2 - m);
      p3 = ex2(e3 - m);
      p4 = ex2(e4 - m);
    } else {
      float mn = fmaxf(m, gm);
      float f = ex2(m - mn);
      p1 = ex2(e1 - mn);
      p2 = ex2(e2 - mn);
      p3 = ex2(e3 - mn);
      p4 = ex2(e4 - mn);
      s *= f;
      a0 *= f; a1 *= f; a2 *= f; a3 *= f;
      a4 *= f; a5 *= f; a6 *= f; a7 *= f;
      m = mn;
    }
    s += (p1 + p2) + (p3 + p4);
    h16x2 p12 = pkrtz(p1, p2), p34 = pkrtz(p3, p4);
    a0 = fdot2f(p12, bc16(PAIR_LO(u1.x, u2.x)), a0);
    a0 = fdot2f(p34, bc16(PAIR_LO(u3.x, u4.x)), a0);
    a1 = fdot2f(p12, bc16(PAIR_HI(u1.x, u2.x)), a1);
    a1 = fdot2f(p34, bc16(PAIR_HI(u3.x, u4.x)), a1);
    a2 = fdot2f(p12, bc16(PAIR_LO(u1.y, u2.y)), a2);
    a2 = fdot2f(p34, bc16(PAIR_LO(u3.y, u4.y)), a2);
    a3 = fdot2f(p12, bc16(PAIR_HI(u1.y, u2.y)), a3);
    a3 = fdot2f(p34, bc16(PAIR_HI(u3.y, u4.y)), a3);
    a4 = fdot2f(p12, bc16(PAIR_LO(u1.z, u2.z)), a4);
    a4 = fdot2f(p34, bc16(PAIR_LO(u3.z, u4.z)), a4);
    a5 = fdot2f(p12, bc16(PAIR_HI(u1.z, u2.z)), a5);
    a5 = fdot2f(p34, bc16(PAIR_HI(u3.z, u4.z)), a5);
    a6 = fdot2f(p12, bc16(PAIR_LO(u1.w, u2.w)), a6);
    a6 = fdot2f(p34, bc16(PAIR_LO(u3.w, u4.w)), a6);
    a7 = fdot2f(p12, bc16(PAIR_HI(u1.w, u2.w)), a7);
    a7 = fdot2f(p34, bc16(PAIR_HI(u3.w, u4.w)), a7);
  }
  for (; p < end; ++p) one_edge(esrc[p]);

  if (valid) {
    float inv = 1.f / (s + 1e-16f);
    ushort8 o;
    o[0] = f2h(a0 * inv); o[1] = f2h(a1 * inv);
    o[2] = f2h(a2 * inv); o[3] = f2h(a3 * inv);
    o[4] = f2h(a4 * inv); o[5] = f2h(a5 * inv);
    o[6] = f2h(a6 * inv); o[7] = f2h(a7 * inv);
    *(ushort8*)&out[(size_t)d * 64 + ch] = o;
  }
}

// ---------------- BN statistics (per-channel sum / sumsq), fp16 input
template<int D_, int RPB>
__global__ __launch_bounds__(256) void bn_stats(const ushort* __restrict__ h,
    float* __restrict__ gsum, float* __restrict__ gsumsq, int nrows)
{
  constexpr int RG = 256 / D_;
  int c = threadIdx.x % D_;
  int rg = threadIdx.x / D_;
  int r0 = blockIdx.x * RPB;
  float s = 0.f, sq = 0.f;
  int rend = min(r0 + RPB, nrows);
  for (int r = r0 + rg; r < rend; r += RG) {
    float v = h2f(h[(size_t)r * D_ + c]);
    s += v;
    sq = fmaf(v, v, sq);
  }
  atomicAdd(&gsum[c], s);
  atomicAdd(&gsumsq[c], sq);
}

// ---------------- fused pooling (BN finalize+apply inline) + classifier MLP.
__global__ __launch_bounds__(256) void pool_mlp(
    const ushort* __restrict__ h3, const int* __restrict__ batch,
    const float* __restrict__ gsum, const float* __restrict__ gsumsq,
    const float* __restrict__ g3, const float* __restrict__ be3,
    const float* __restrict__ Wc1, const float* __restrict__ bc1,
    const float* __restrict__ Wc2, const float* __restrict__ bc2,
    float* __restrict__ outp)
{
  int g = blockIdx.x;
  int t = threadIdx.x;
  int lane = t & 63, w = t >> 6;
  int lo, hi;
  {
    int a = 0, b = N_NODES;
    while (a < b) { int mid = (a + b) >> 1; if (batch[mid] < g) a = mid + 1; else b = mid; }
    lo = a;
    b = N_NODES;
    while (a < b) { int mid = (a + b) >> 1; if (batch[mid] < g + 1) a = mid + 1; else b = mid; }
    hi = a;
  }
  const float invn = 1.0f / (float)N_NODES;
  float mu = gsum[lane] * invn;
  float var = gsumsq[lane] * invn - mu * mu;
  float scl = g3[lane] * rsqrtf(var + 1e-5f);
  float shf = be3[lane] - mu * scl;
  float s = 0.f, mx = -INFINITY;
  for (int r = lo + w; r < hi; r += 4) {
    float v = fmaf(h2f(h3[(size_t)r * 64 + lane]), scl, shf);
    s += v;
    mx = fmaxf(mx, v);
  }
  __shared__ float ssum[4][64];
  __shared__ float smax[4][64];
  __shared__ float pooled[128];
  ssum[w][lane] = s;
  smax[w][lane] = mx;
  __syncthreads();
  if (w == 0) {
    float tot = ssum[0][lane] + ssum[1][lane] + ssum[2][lane] + ssum[3][lane];
    float m4 = fmaxf(fmaxf(smax[0][lane], smax[1][lane]),
                     fmaxf(smax[2][lane], smax[3][lane]));
    float cnt = (float)(hi - lo);
    pooled[lane] = tot / fmaxf(cnt, 1.f);
    pooled[64 + lane] = m4;
  }
  __syncthreads();
  if (w == 0) {
    float a = bc1[lane];
    #pragma unroll 8
    for (int k = 0; k < 128; ++k) a = fmaf(pooled[k], Wc1[k * 64 + lane], a);
    a = fmaxf(a, 0.f);
    float v = a * Wc2[lane];
    v += __shfl_xor(v, 1);
    v += __shfl_xor(v, 2);
    v += __shfl_xor(v, 4);
    v += __shfl_xor(v, 8);
    v += __shfl_xor(v, 16);
    v += __shfl_xor(v, 32);
    if (lane == 0) outp[g] = v + bc2[0];
  }
}

extern "C" void kernel_launch(void* const* d_in, const int* in_sizes, int n_in,
                              void* d_out, int out_size, void* d_ws, size_t ws_size,
                              hipStream_t stream)
{
  const float* x    = (const float*)d_in[0];
  const int*   ei   = (const int*)d_in[1];
  const int*   batch= (const int*)d_in[2];
  const float* Wl1  = (const float*)d_in[3];
  const float* Wr1  = (const float*)d_in[4];
  const float* att1 = (const float*)d_in[5];
  // b1/b2/b3 cancel in the following BatchNorm -> unused
  const float* g1   = (const float*)d_in[7];
  const float* be1  = (const float*)d_in[8];
  const float* Wl2  = (const float*)d_in[9];
  const float* Wr2  = (const float*)d_in[10];
  const float* att2 = (const float*)d_in[11];
  const float* g2   = (const float*)d_in[13];
  const float* be2  = (const float*)d_in[14];
  const float* Wl3  = (const float*)d_in[15];
  const float* Wr3  = (const float*)d_in[16];
  const float* att3 = (const float*)d_in[17];
  const float* g3   = (const float*)d_in[19];
  const float* be3  = (const float*)d_in[20];
  const float* Wc1  = (const float*)d_in[21];
  const float* bc1  = (const float*)d_in[22];
  const float* Wc2  = (const float*)d_in[23];
  const float* bc2  = (const float*)d_in[24];

  const int* srcs = ei;
  const int* dsts = ei + N_EDGES;

  float* ws = (float*)d_ws;
  size_t o = 0;
  ushort* XLB = (ushort*)(ws + o); o += (size_t)N_NODES * HIDD / 2;  // fp16 xl
  ushort* XRB = (ushort*)(ws + o); o += (size_t)N_NODES * HIDD / 2;  // fp16 xr
  ushort* Hb = (ushort*)(ws + o);  o += (size_t)N_NODES * HIDD / 2;  // fp16 GAT out
  ushort* BT2 = (ushort*)(ws + o); o += (size_t)4 * 32 * 256 * 8 / 2;   // 2 mats x 2 halves
  ushort* BT3 = (ushort*)(ws + o); o += (size_t)4 * 32 * 64 * 8 / 2;
  int* ESRC = (int*)(ws + o);    o += ET;
  int* ROWS = (int*)(ws + o);    o += N_NODES + 1;
  int* CURS = (int*)(ws + o);    o += N_NODES;
  int* BSUM = (int*)(ws + o);    o += SCAN_BLOCKS;
  int* BOFF = (int*)(ws + o);    o += SCAN_BLOCKS;
  float* GS  = ws + o;           o += 256;
  float* GSQ = ws + o;           o += 256;

  const int ROW_BLOCKS = (N_NODES + 63) / 64;
  const int ROW_BLOCKS32 = (N_NODES + 31) / 32;
  const int DST_BLOCKS = (N_NODES + 3) / 4;
  constexpr int PLANE2 = 32 * 256 * 8;
  constexpr int PLANE3 = 32 * 64 * 8;

  // ================= weight transpose/split (independent; run once up front)
  convertB<256, 256><<<(65536 + 255) / 256, 256, 0, stream>>>(Wl2, BT2);
  convertB<256, 256><<<(65536 + 255) / 256, 256, 0, stream>>>(Wr2, BT2 + 2 * PLANE2);
  convertB<256, 64><<<(16384 + 255) / 256, 256, 0, stream>>>(Wl3, BT3);
  convertB<256, 64><<<(16384 + 255) / 256, 256, 0, stream>>>(Wr3, BT3 + 2 * PLANE3);

  // ================= CSR build (reused by all 3 layers) =================
  hipMemsetAsync(CURS, 0, N_NODES * 4, stream);
  hist_kernel<<<(ET + 255) / 256, 256, 0, stream>>>(dsts, CURS);
  scan_part<<<SCAN_BLOCKS, 256, 0, stream>>>(CURS, ROWS, BSUM);
  scan_bsums<<<1, 256, 0, stream>>>(BSUM, BOFF);
  scan_apply<<<SCAN_BLOCKS, 256, 0, stream>>>(ROWS, BOFF, CURS);
  scatter_kernel<<<(ET + 255) / 256, 256, 0, stream>>>(srcs, dsts, CURS, ESRC);

  // ================= layer 1 (16 -> 4x64, concat): fp32 vector GEMM ======
  gemm_dual<16, 256><<<dim3(ROW_BLOCKS, 4), 256, 0, stream>>>(
      x, Wl1, Wr1, XLB, XRB, N_NODES);
  flash256<<<DST_BLOCKS, 256, 0, stream>>>(XLB, XRB, att1, ROWS, ESRC, Hb);
  hipMemsetAsync(GS, 0, 512 * 4, stream);
  bn_stats<256, 64><<<ROW_BLOCKS, 256, 0, stream>>>(Hb, GS, GSQ, N_NODES);

  // ================= layer 2 (256 -> 4x64): fully-fused BN+ELU+MFMA GEMM ==
  gemm_fused<256><<<ROW_BLOCKS32, 512, 0, stream>>>(
      Hb, GS, GSQ, g1, be1, BT2, XLB, XRB);
  flash256<<<DST_BLOCKS, 256, 0, stream>>>(XLB, XRB, att2, ROWS, ESRC, Hb);
  hipMemsetAsync(GS, 0, 512 * 4, stream);
  bn_stats<256, 64><<<ROW_BLOCKS, 256, 0, stream>>>(Hb, GS, GSQ, N_NODES);

  // ================= layer 3 (256 -> 64, 1 head): fused MFMA GEMM ========
  gemm_fused<64><<<ROW_BLOCKS32, 128, 0, stream>>>(
      Hb, GS, GSQ, g2, be2, BT3, XLB, XRB);
  flash64<<<(N_NODES + 31) / 32, 256, 0, stream>>>(XLB, XRB, att3, ROWS, ESRC, Hb);
  hipMemsetAsync(GS, 0, 512 * 4, stream);
  bn_stats<64, 256><<<(N_NODES + 255) / 256, 256, 0, stream>>>(Hb, GS, GSQ, N_NODES);

  // ================= fused pooling (BN inline) + classifier ==============
  pool_mlp<<<N_GRAPHS, 256, 0, stream>>>(Hb, batch, GS, GSQ, g3, be3,
                                         Wc1, bc1, Wc2, bc2, (float*)d_out);
}